// Round 1
// 679.985 us; speedup vs baseline: 1.0219x; 1.0219x over previous
//
#include <hip/hip_runtime.h>

typedef __bf16 bf16;
typedef __bf16 bf16x8 __attribute__((ext_vector_type(8)));
typedef __bf16 bf16x4 __attribute__((ext_vector_type(4)));
typedef float f32x4 __attribute__((ext_vector_type(4)));

#define S_LEN 2048
#define HID 4096
#define NH 32
#define NKV 8
#define HD 128
#define QSTR 6144                      // fused qkv row stride
#define SCALE 0.08838834764831845f
#define QSCL 0.1275164918918885f       // SCALE * log2(e)
#define M2C 16.33f                     // >= 128*QSCL = 16.3221 (Cauchy-Schwarz hard bound)

__device__ __forceinline__ bf16x8 load8(const bf16* p) { return *(const bf16x8*)p; }
__device__ __forceinline__ bf16x8 load8(const float* p) {
    float4 a = *(const float4*)p;
    float4 b = *(const float4*)(p + 4);
    bf16x8 r;
    r[0] = (bf16)a.x; r[1] = (bf16)a.y; r[2] = (bf16)a.z; r[3] = (bf16)a.w;
    r[4] = (bf16)b.x; r[5] = (bf16)b.y; r[6] = (bf16)b.z; r[7] = (bf16)b.w;
    return r;
}

__device__ __forceinline__ void load_lds16(const bf16* g, bf16* l) {
    __builtin_amdgcn_global_load_lds(
        (const __attribute__((address_space(1))) void*)g,
        (__attribute__((address_space(3))) void*)l, 16, 0, 0);
}

template <int C> __device__ __forceinline__ void vmwait() {
    asm volatile("s_waitcnt vmcnt(%0)" ::"n"(C) : "memory");
}

// ---------------------------------------------------------------------------
// fp32 -> bf16 bulk convert
// ---------------------------------------------------------------------------
__global__ __launch_bounds__(256) void cvt(const float* __restrict__ in,
                                           bf16* __restrict__ out, int n8) {
    int i = blockIdx.x * 256 + threadIdx.x;
    if (i < n8) *(bf16x8*)&out[i * 8] = load8(&in[(size_t)i * 8]);
}

// ---------------------------------------------------------------------------
// Pipelined GEMM: out[M,N] = A[M,K] @ B[N,K]^T + bias (bf16 in, fp32 accum).
// Counted-vmcnt structure (T1+T2+T3/T4+T5): BK=32 K-tiles, 4-deep LDS ring,
// stage 3 tiles ahead via global_load_lds, raw s_barrier + manual vmcnt
// (8 steady / 4 / 0 tail), setprio around the MFMA cluster, XOR granule
// swizzle (pre-swizzled global source, linear LDS dest, swizzled ds_read).
// 8 waves (WM x WN), per-wave output (BM/WM) x (BN/WN).
// BMODE 0: bias=b0[n].  BMODE 1: packed-QKV bias (b0 <4096, b1 <5120, b2).
// Requires K % 32 == 0, K/32 >= 4, BM|M, BN|N.
// ---------------------------------------------------------------------------
template <int BM, int BN, int WM, int WN, int BMODE, typename TO>
__global__ __launch_bounds__(512, 2) void gemm_p(const bf16* __restrict__ A,
                                                 const bf16* __restrict__ Bw,
                                                 const float* __restrict__ b0,
                                                 const float* __restrict__ b1,
                                                 const float* __restrict__ b2,
                                                 TO* __restrict__ out,
                                                 int N, int K) {
    constexpr int RW  = BM / WM;           // rows per wave
    constexpr int CW  = BN / WN;           // cols per wave
    constexpr int FM  = RW / 16;           // m fragments
    constexpr int FN  = CW / 16;           // n fragments
    constexpr int ALD = (BM * 4) / 512;    // 16B loads per thread, A tile (BM x 32)
    constexpr int BLD = (BN * 4) / 512;
    constexpr int LPT = ALD + BLD;         // loads per thread per K-tile

    __shared__ __align__(16) bf16 As[4][BM * 32];
    __shared__ __align__(16) bf16 Bs[4][BN * 32];

    const int tid  = threadIdx.x;
    const int wave = tid >> 6;
    const int lane = tid & 63;
    const int quad = lane >> 4;
    const int l16  = lane & 15;
    const int wm   = wave / WN;
    const int wn   = wave % WN;

    // XCD-aware bijective block swizzle (all grids here are % 8 == 0)
    const int gx   = gridDim.x;
    const int nwg  = gx * gridDim.y;
    const int orig = blockIdx.y * gx + blockIdx.x;
    int wg = orig;
    if ((nwg & 7) == 0) wg = (orig & 7) * (nwg >> 3) + (orig >> 3);
    const int row0 = (wg / gx) * BM;
    const int col0 = (wg % gx) * BN;

    const int NT = K >> 5;

    auto stage = [&](int buf, int kt) {
#pragma unroll
        for (int j = 0; j < ALD; ++j) {
            int c = j * 512 + tid;              // 16B granule index (linear LDS dest)
            int r = c >> 2;                     // row within tile
            int g = (c & 3) ^ ((c >> 3) & 3);   // pre-swizzled source granule
            load_lds16(&A[(size_t)(row0 + r) * K + kt * 32 + g * 8], &As[buf][c * 8]);
        }
#pragma unroll
        for (int j = 0; j < BLD; ++j) {
            int c = j * 512 + tid;
            int r = c >> 2;
            int g = (c & 3) ^ ((c >> 3) & 3);
            load_lds16(&Bw[(size_t)(col0 + r) * K + kt * 32 + g * 8], &Bs[buf][c * 8]);
        }
    };

    f32x4 acc[FM][FN];
#pragma unroll
    for (int mi = 0; mi < FM; ++mi)
#pragma unroll
        for (int ni = 0; ni < FN; ++ni) { f32x4 z = {0.f, 0.f, 0.f, 0.f}; acc[mi][ni] = z; }

    // prologue: fill 3 ring slots, drain the oldest tile only
    stage(0, 0);
    stage(1, 1);
    stage(2, 2);
    vmwait<2 * LPT>();
    __builtin_amdgcn_s_barrier();
    __builtin_amdgcn_sched_barrier(0);

    const int swz  = (l16 >> 1) & 3;
    const int arow = wm * RW + l16;
    const int brow = wn * CW + l16;
    const int goff = (quad ^ swz) << 3;

    for (int t = 0; t < NT; ++t) {
        const int buf = t & 3;
        // issue next-next-next tile's loads first (lands into slot last read at t-1)
        if (t + 3 < NT) stage((t + 3) & 3, t + 3);

        bf16x8 af[FM], bfr[FN];
#pragma unroll
        for (int mi = 0; mi < FM; ++mi)
            af[mi] = *(const bf16x8*)&As[buf][(arow + mi * 16) * 32 + goff];
#pragma unroll
        for (int ni = 0; ni < FN; ++ni)
            bfr[ni] = *(const bf16x8*)&Bs[buf][(brow + ni * 16) * 32 + goff];

        __builtin_amdgcn_s_setprio(1);
#pragma unroll
        for (int mi = 0; mi < FM; ++mi)
#pragma unroll
            for (int ni = 0; ni < FN; ++ni)
                acc[mi][ni] = __builtin_amdgcn_mfma_f32_16x16x32_bf16(
                    af[mi], bfr[ni], acc[mi][ni], 0, 0, 0);
        __builtin_amdgcn_s_setprio(0);

        // counted drain: leave 2 tiles (steady) / 1 / 0 in flight; never full-drain early
        if (t + 3 < NT)      vmwait<2 * LPT>();
        else if (t + 2 < NT) vmwait<LPT>();
        else if (t + 1 < NT) vmwait<0>();
        __builtin_amdgcn_s_barrier();
        __builtin_amdgcn_sched_barrier(0);
    }

#pragma unroll
    for (int ni = 0; ni < FN; ++ni) {
        int n = col0 + wn * CW + ni * 16 + l16;
        float bv;
        if (BMODE == 0) bv = b0[n];
        else bv = (n < 4096) ? b0[n] : ((n < 5120) ? b1[n - 4096] : b2[n - 5120]);
#pragma unroll
        for (int mi = 0; mi < FM; ++mi) {
            int m = row0 + wm * RW + mi * 16 + quad * 4;
#pragma unroll
            for (int reg = 0; reg < 4; ++reg)
                out[(size_t)(m + reg) * N + n] = (TO)(acc[mi][ni][reg] + bv);
        }
    }
}

// ---------------------------------------------------------------------------
// LayerNorm(HD=128) + RoPE in place on fused qkv buffer (stride QSTR).
// q rows additionally pre-scaled by QSCL (softmax works in log2 domain).
// ---------------------------------------------------------------------------
__global__ __launch_bounds__(256) void ln_rope(bf16* __restrict__ qkv,
                                               const float* __restrict__ qg, const float* __restrict__ qbt,
                                               const float* __restrict__ kg, const float* __restrict__ kbt) {
    int row  = blockIdx.x * 4 + (threadIdx.x >> 6);
    int lane = threadIdx.x & 63;

    bf16* ptr;
    const float *g, *bb;
    int s;
    float osc;
    if (row < S_LEN * NH) {
        s   = row >> 5;
        ptr = qkv + (size_t)s * QSTR + (row & 31) * HD;
        g   = qg; bb = qbt; osc = QSCL;
    } else {
        int r2 = row - S_LEN * NH;
        s   = r2 >> 3;
        ptr = qkv + (size_t)s * QSTR + 4096 + (r2 & 7) * HD;
        g   = kg; bb = kbt; osc = 1.f;
    }

    float x1 = (float)ptr[lane];
    float x2 = (float)ptr[lane + 64];
    float sum = x1 + x2;
    float sq  = x1 * x1 + x2 * x2;
#pragma unroll
    for (int m = 1; m < 64; m <<= 1) {
        sum += __shfl_xor(sum, m);
        sq  += __shfl_xor(sq, m);
    }
    float mu  = sum * (1.f / 128.f);
    float var = sq * (1.f / 128.f) - mu * mu;
    float rs  = rsqrtf(var + 1e-5f);
    float n1  = (x1 - mu) * rs * g[lane] + bb[lane];
    float n2  = (x2 - mu) * rs * g[lane + 64] + bb[lane + 64];

    float inv = powf(500000.f, -(float)lane * (1.f / 64.f));
    float ang = (float)s * inv;
    float sn, cs;
    sincosf(ang, &sn, &cs);

    ptr[lane]      = (bf16)((n1 * cs - n2 * sn) * osc);
    ptr[lane + 64] = (bf16)((n2 * cs + n1 * sn) * osc);
}

// ---------------------------------------------------------------------------
// Transpose v (cols 5120..6143 of qkv, [s][c]) -> vT [c][s]. 64x64 LDS tiles,
// XOR-swizzled (write b128 free; read 8xb16 2-way = free).
// ---------------------------------------------------------------------------
__global__ __launch_bounds__(256) void transpose_v(const bf16* __restrict__ qkv,
                                                   bf16* __restrict__ vT) {
    __shared__ bf16 Ts[64 * 64];
    const int c0 = blockIdx.x * 64;
    const int s0 = blockIdx.y * 64;
    const int tid = threadIdx.x;

#pragma unroll
    for (int i = 0; i < 2; ++i) {
        int cc = i * 256 + tid;
        int r = cc >> 3, col8 = cc & 7;
        *(bf16x8*)&Ts[r * 64 + ((col8 ^ (r & 7)) << 3)] =
            *(const bf16x8*)&qkv[(size_t)(s0 + r) * QSTR + 5120 + c0 + (col8 << 3)];
    }
    __syncthreads();
#pragma unroll
    for (int i = 0; i < 2; ++i) {
        int oc = i * 256 + tid;
        int c = oc & 63, sb = oc >> 6;
        bf16x8 r8;
#pragma unroll
        for (int j = 0; j < 8; ++j) {
            int sg = sb * 8 + j;
            r8[j] = Ts[sg * 64 + ((((c >> 3) ^ (sg & 7)) << 3) + (c & 7))];
        }
        *(bf16x8*)&vT[(size_t)(c0 + c) * S_LEN + s0 + sb * 8] = r8;
    }
}

// ---------------------------------------------------------------------------
// Flash attention v3: fixed-max softmax (log2 domain), balanced split-K.
// Block = (pair p, split sp, kvh). Processes Q-tiles p and 63-p (32 rows),
// K-tiles kt == sp (mod 2). Wave w owns head kvh*4+w. Register-prefetched
// staging. Row sums via MFMA ones-trick. Writes fp32 partials OP[sp] + l.
// ---------------------------------------------------------------------------
__global__ __launch_bounds__(256, 2) void attn3(const bf16* __restrict__ qkv,
                                                const bf16* __restrict__ vT,
                                                float* __restrict__ OP,
                                                float* __restrict__ lbuf) {
    const int pairp = blockIdx.x >> 1;
    const int sp    = blockIdx.x & 1;
    const int kvh   = blockIdx.y;
    const int tid   = threadIdx.x;
    const int wave  = tid >> 6;
    const int lane  = tid & 63;
    const int quad  = lane >> 4;
    const int l16   = lane & 15;
    const int h     = kvh * 4 + wave;

    __shared__ __align__(16) bf16 Ks[64 * 128];
    __shared__ __align__(16) bf16 Vt[128 * 64];
    __shared__ __align__(16) bf16 Ps[4][32 * 64];

    float* OPs = OP + (size_t)sp * (S_LEN * HID);
    float* lbs = lbuf + sp * (S_LEN * NH);

    bf16x8 onesf;
#pragma unroll
    for (int j = 0; j < 8; ++j) onesf[j] = (bf16)1.f;

    int4 pk[4], pv[4];

    for (int ph = 0; ph < 2; ++ph) {
        const int qt  = ph ? (63 - pairp) : pairp;
        const int r0  = qt * 32;
        const int nkt = qt / 2 + 1;
        const int nit = (nkt + 1 - sp) / 2;   // kt = sp + 2*it < nkt

        // Q fragments (already scaled by QSCL in ln_rope)
        bf16x8 qf[2][4];
#pragma unroll
        for (int mi = 0; mi < 2; ++mi)
#pragma unroll
            for (int ks = 0; ks < 4; ++ks)
                qf[mi][ks] = *(const bf16x8*)&qkv[(size_t)(r0 + mi * 16 + l16) * QSTR +
                                                  h * HD + ks * 32 + quad * 8];

        f32x4 o_acc[2][8];
#pragma unroll
        for (int mi = 0; mi < 2; ++mi)
#pragma unroll
            for (int ni = 0; ni < 8; ++ni) {
                f32x4 z = {0.f, 0.f, 0.f, 0.f};
                o_acc[mi][ni] = z;
            }
        f32x4 lacc[2];
#pragma unroll
        for (int mi = 0; mi < 2; ++mi) { f32x4 z = {0.f, 0.f, 0.f, 0.f}; lacc[mi] = z; }

        auto load_regs = [&](int kt) {
#pragma unroll
            for (int i = 0; i < 4; ++i) {
                int cc = i * 256 + tid;
                int key = cc >> 4, d8 = cc & 15;
                pk[i] = *(const int4*)&qkv[(size_t)(kt * 64 + key) * QSTR + 4096 +
                                           kvh * HD + (d8 << 3)];
            }
#pragma unroll
            for (int i = 0; i < 4; ++i) {
                int cc = i * 256 + tid;
                int d = cc >> 3, k8 = cc & 7;
                pv[i] = *(const int4*)&vT[(size_t)(kvh * HD + d) * S_LEN + kt * 64 + (k8 << 3)];
            }
        };

        if (nit > 0) load_regs(sp);

        for (int it = 0; it < nit; ++it) {
            const int kt = sp + 2 * it;
            // drain prefetch regs into swizzled LDS
#pragma unroll
            for (int i = 0; i < 4; ++i) {
                int cc = i * 256 + tid;
                int key = cc >> 4, d8 = cc & 15;
                *(int4*)&Ks[key * 128 + ((d8 ^ (key & 7)) << 3)] = pk[i];
            }
#pragma unroll
            for (int i = 0; i < 4; ++i) {
                int cc = i * 256 + tid;
                int d = cc >> 3, k8 = cc & 7;
                *(int4*)&Vt[d * 64 + ((k8 ^ (d & 7)) << 3)] = pv[i];
            }
            __syncthreads();

            if (it + 1 < nit) load_regs(kt + 2);   // prefetch next tile

            // S = Q K^T (log2-scaled)
            f32x4 sacc[2][4];
#pragma unroll
            for (int mi = 0; mi < 2; ++mi)
#pragma unroll
                for (int ni = 0; ni < 4; ++ni) {
                    f32x4 z = {0.f, 0.f, 0.f, 0.f};
                    sacc[mi][ni] = z;
                }
#pragma unroll
            for (int ks = 0; ks < 4; ++ks)
#pragma unroll
                for (int ni = 0; ni < 4; ++ni) {
                    bf16x8 kf = *(const bf16x8*)&Ks[(ni * 16 + l16) * 128 +
                                                    ((((ks << 2) + quad) ^ (l16 & 7)) << 3)];
                    sacc[0][ni] = __builtin_amdgcn_mfma_f32_16x16x32_bf16(qf[0][ks], kf, sacc[0][ni], 0, 0, 0);
                    sacc[1][ni] = __builtin_amdgcn_mfma_f32_16x16x32_bf16(qf[1][ks], kf, sacc[1][ni], 0, 0, 0);
                }

            // fixed-max softmax: p = exp2(s2 - M2C); masked -> 0
#pragma unroll
            for (int mi = 0; mi < 2; ++mi)
#pragma unroll
                for (int reg = 0; reg < 4; ++reg) {
                    int rloc = mi * 16 + quad * 4 + reg;
                    int qrow = r0 + rloc;
#pragma unroll
                    for (int ni = 0; ni < 4; ++ni) {
                        int key = kt * 64 + ni * 16 + l16;
                        float t = (key > qrow) ? -1e30f : (sacc[mi][ni][reg] - M2C);
                        float p = exp2f(t);
                        int blk = (ni * 2 + (l16 >> 3)) ^ (rloc & 7);
                        Ps[wave][rloc * 64 + blk * 8 + (l16 & 7)] = (bf16)p;
                    }
                }

            // O += P @ V ; l += P @ ones  (per-wave Ps: no barrier needed)
#pragma unroll
            for (int ks2 = 0; ks2 < 2; ++ks2) {
                bf16x8 pa[2];
#pragma unroll
                for (int mi = 0; mi < 2; ++mi) {
                    int rloc = mi * 16 + l16;
                    pa[mi] = *(const bf16x8*)&Ps[wave][rloc * 64 +
                                                       ((((ks2 << 2) + quad) ^ (rloc & 7)) << 3)];
                }
#pragma unroll
                for (int ni = 0; ni < 8; ++ni) {
                    int d = ni * 16 + l16;
                    bf16x8 vf = *(const bf16x8*)&Vt[d * 64 + ((((ks2 << 2) + quad) ^ (d & 7)) << 3)];
                    o_acc[0][ni] = __builtin_amdgcn_mfma_f32_16x16x32_bf16(pa[0], vf, o_acc[0][ni], 0, 0, 0);
                    o_acc[1][ni] = __builtin_amdgcn_mfma_f32_16x16x32_bf16(pa[1], vf, o_acc[1][ni], 0, 0, 0);
                }
                lacc[0] = __builtin_amdgcn_mfma_f32_16x16x32_bf16(pa[0], onesf, lacc[0], 0, 0, 0);
                lacc[1] = __builtin_amdgcn_mfma_f32_16x16x32_bf16(pa[1], onesf, lacc[1], 0, 0, 0);
            }
            __syncthreads();
        }

        // partial epilogue (always runs; zeros if nit==0)
#pragma unroll
        for (int mi = 0; mi < 2; ++mi)
#pragma unroll
            for (int reg = 0; reg < 4; ++reg) {
                int s = r0 + mi * 16 + quad * 4 + reg;
#pragma unroll
                for (int ni = 0; ni < 8; ++ni)
                    OPs[(size_t)s * HID + h * HD + ni * 16 + l16] = o_acc[mi][ni][reg];
                if (l16 == 0) lbs[s * NH + h] = lacc[mi][reg];
            }
    }
}

// ---------------------------------------------------------------------------
// merge: abuf[s][h*128+d] = (OP0 + OP1) / (l0 + l1)
// ---------------------------------------------------------------------------
__global__ __launch_bounds__(256) void merge(const float* __restrict__ OP,
                                             const float* __restrict__ lb,
                                             bf16* __restrict__ abuf) {
    int g = blockIdx.x * 256 + threadIdx.x;      // 0 .. 2048*1024-1
    int s = g >> 10;
    int col = (g & 1023) << 2;
    int h = col >> 7;
    float l = lb[s * NH + h] + lb[S_LEN * NH + s * NH + h];
    float inv = 1.f / fmaxf(l, 1e-30f);
    f32x4 o0 = *(const f32x4*)&OP[(size_t)g << 2];
    f32x4 o1 = *(const f32x4*)&OP[((size_t)g << 2) + (size_t)S_LEN * HID];
    bf16x4 r;
#pragma unroll
    for (int j = 0; j < 4; ++j) r[j] = (bf16)((o0[j] + o1[j]) * inv);
    *(bf16x4*)&abuf[(size_t)s * HID + col] = r;
}

// ===========================================================================
// Fallback path (round-3, proven) — only if workspace is unexpectedly small.
// ===========================================================================
template <typename TA, typename TO>
__global__ __launch_bounds__(256) void gemm_bt(const TA* __restrict__ A,
                                               const float* __restrict__ W,
                                               const float* __restrict__ bias,
                                               TO* __restrict__ out,
                                               int N, int K) {
    __shared__ __align__(16) bf16 As[128 * 64];
    __shared__ __align__(16) bf16 Bs[128 * 64];
    const int tid = threadIdx.x, wave = tid >> 6, lane = tid & 63;
    const int quad = lane >> 4, l16 = lane & 15, wm = wave >> 1, wn = wave & 1;
    const int row0 = blockIdx.y * 128, col0 = blockIdx.x * 128;
    f32x4 acc[4][4];
#pragma unroll
    for (int mi = 0; mi < 4; ++mi)
#pragma unroll
        for (int ni = 0; ni < 4; ++ni) { f32x4 z = {0.f,0.f,0.f,0.f}; acc[mi][ni] = z; }
    for (int k0 = 0; k0 < K; k0 += 64) {
#pragma unroll
        for (int i = 0; i < 4; ++i) {
            int c = i * 256 + tid, r = c >> 3, col8 = (c & 7) << 3;
            *(bf16x8*)&As[r * 64 + col8] = load8(&A[(size_t)(row0 + r) * K + k0 + col8]);
            *(bf16x8*)&Bs[r * 64 + col8] = load8(&W[(size_t)(col0 + r) * K + k0 + col8]);
        }
        __syncthreads();
#pragma unroll
        for (int ks = 0; ks < 2; ++ks) {
            bf16x8 af[4], bfr[4];
#pragma unroll
            for (int mi = 0; mi < 4; ++mi)
                af[mi] = *(const bf16x8*)&As[(wm * 64 + mi * 16 + l16) * 64 + ks * 32 + quad * 8];
#pragma unroll
            for (int ni = 0; ni < 4; ++ni)
                bfr[ni] = *(const bf16x8*)&Bs[(wn * 64 + ni * 16 + l16) * 64 + ks * 32 + quad * 8];
#pragma unroll
            for (int mi = 0; mi < 4; ++mi)
#pragma unroll
                for (int ni = 0; ni < 4; ++ni)
                    acc[mi][ni] = __builtin_amdgcn_mfma_f32_16x16x32_bf16(af[mi], bfr[ni], acc[mi][ni], 0, 0, 0);
        }
        __syncthreads();
    }
#pragma unroll
    for (int ni = 0; ni < 4; ++ni) {
        int n = col0 + wn * 64 + ni * 16 + l16;
        float bv = bias[n];
#pragma unroll
        for (int mi = 0; mi < 4; ++mi) {
            int m = row0 + wm * 64 + mi * 16 + quad * 4;
#pragma unroll
            for (int reg = 0; reg < 4; ++reg)
                out[(size_t)(m + reg) * N + n] = (TO)(acc[mi][ni][reg] + bv);
        }
    }
}

__global__ __launch_bounds__(256) void ln_rope_f(bf16* __restrict__ qb, bf16* __restrict__ kb,
                                                 const float* __restrict__ qg, const float* __restrict__ qbt,
                                                 const float* __restrict__ kg, const float* __restrict__ kbt) {
    int row = blockIdx.x * 4 + (threadIdx.x >> 6);
    int lane = threadIdx.x & 63;
    bf16* ptr; const float *g, *bb; int s;
    if (row < S_LEN * NH) { s = row >> 5; ptr = qb + (size_t)s * (NH * HD) + (row & 31) * HD; g = qg; bb = qbt; }
    else { int r2 = row - S_LEN * NH; s = r2 >> 3; ptr = kb + (size_t)s * (NKV * HD) + (r2 & 7) * HD; g = kg; bb = kbt; }
    float x1 = (float)ptr[lane], x2 = (float)ptr[lane + 64];
    float sum = x1 + x2, sq = x1 * x1 + x2 * x2;
#pragma unroll
    for (int m = 1; m < 64; m <<= 1) { sum += __shfl_xor(sum, m); sq += __shfl_xor(sq, m); }
    float mu = sum * (1.f / 128.f), var = sq * (1.f / 128.f) - mu * mu;
    float rs = rsqrtf(var + 1e-5f);
    float n1 = (x1 - mu) * rs * g[lane] + bb[lane];
    float n2 = (x2 - mu) * rs * g[lane + 64] + bb[lane + 64];
    float inv = powf(500000.f, -(float)lane * (1.f / 64.f));
    float ang = (float)s * inv, sn, cs;
    sincosf(ang, &sn, &cs);
    ptr[lane] = (bf16)(n1 * cs - n2 * sn);
    ptr[lane + 64] = (bf16)(n2 * cs + n1 * sn);
}

__global__ __launch_bounds__(256) void attn_old(const bf16* __restrict__ qbuf,
                                                const bf16* __restrict__ kbuf,
                                                const bf16* __restrict__ vbuf,
                                                bf16* __restrict__ obuf) {
    const int qi = blockIdx.x, hh = blockIdx.y, kvh = hh >> 2;
    __shared__ __align__(16) bf16 Qs[64 * 128];
    __shared__ __align__(16) bf16 Ks2[64 * 128];
    __shared__ __align__(16) bf16 Vt2[128 * 80];
    __shared__ __align__(16) float Ss[64 * 64];
    __shared__ __align__(16) bf16 Ps2[64 * 64];
    __shared__ float mS[64], lS[64], aS[64];
    const int tid = threadIdx.x, wave = tid >> 6, lane = tid & 63;
    const int quad = lane >> 4, l16 = lane & 15;
#pragma unroll
    for (int i = 0; i < 4; ++i) {
        int c = i * 256 + tid, r = c >> 4, col8 = (c & 15) << 3;
        *(int4*)&Qs[r * 128 + col8] = *(const int4*)&qbuf[(size_t)(qi * 64 + r) * HID + hh * HD + col8];
    }
    if (tid < 64) { mS[tid] = -1e30f; lS[tid] = 0.f; }
    f32x4 o_acc[8];
#pragma unroll
    for (int i = 0; i < 8; ++i) { f32x4 z = {0.f,0.f,0.f,0.f}; o_acc[i] = z; }
    __syncthreads();
    for (int kt = 0; kt <= qi; ++kt) {
#pragma unroll
        for (int i = 0; i < 4; ++i) {
            int c = i * 256 + tid, r = c >> 4, col8 = (c & 15) << 3;
            const size_t gofs = (size_t)(kt * 64 + r) * (NKV * HD) + kvh * HD + col8;
            *(int4*)&Ks2[r * 128 + col8] = *(const int4*)&kbuf[gofs];
            bf16x8 vv = *(const bf16x8*)&vbuf[gofs];
#pragma unroll
            for (int e = 0; e < 8; ++e) Vt2[(col8 + e) * 80 + r] = vv[e];
        }
        __syncthreads();
        f32x4 sacc[4];
#pragma unroll
        for (int ni = 0; ni < 4; ++ni) { f32x4 z = {0.f,0.f,0.f,0.f}; sacc[ni] = z; }
#pragma unroll
        for (int ks = 0; ks < 4; ++ks) {
            bf16x8 a = *(const bf16x8*)&Qs[(wave * 16 + l16) * 128 + ks * 32 + quad * 8];
#pragma unroll
            for (int ni = 0; ni < 4; ++ni) {
                bf16x8 b = *(const bf16x8*)&Ks2[(ni * 16 + l16) * 128 + ks * 32 + quad * 8];
                sacc[ni] = __builtin_amdgcn_mfma_f32_16x16x32_bf16(a, b, sacc[ni], 0, 0, 0);
            }
        }
#pragma unroll
        for (int ni = 0; ni < 4; ++ni)
#pragma unroll
            for (int reg = 0; reg < 4; ++reg) {
                int r = wave * 16 + quad * 4 + reg, cc = ni * 16 + l16;
                float sv = sacc[ni][reg] * SCALE;
                if (kt * 64 + cc > qi * 64 + r) sv = -1e30f;
                Ss[r * 64 + cc] = sv;
            }
        __syncthreads();
        {
            int r = tid >> 2, j = tid & 3;
            float vals[16], mloc = -1e30f;
#pragma unroll
            for (int c = 0; c < 16; ++c) { vals[c] = Ss[r * 64 + j * 16 + c]; mloc = fmaxf(mloc, vals[c]); }
            mloc = fmaxf(mloc, __shfl_xor(mloc, 1));
            mloc = fmaxf(mloc, __shfl_xor(mloc, 2));
            float mold = mS[r], mnew = fmaxf(mold, mloc), ssum = 0.f;
#pragma unroll
            for (int c = 0; c < 16; ++c) {
                float p = __expf(vals[c] - mnew);
                ssum += p;
                Ps2[r * 64 + j * 16 + c] = (bf16)p;
            }
            ssum += __shfl_xor(ssum, 1);
            ssum += __shfl_xor(ssum, 2);
            if (j == 0) { float alpha = __expf(mold - mnew); mS[r] = mnew; lS[r] = lS[r] * alpha + ssum; aS[r] = alpha; }
        }
        __syncthreads();
        {
            float al2[4];
#pragma unroll
            for (int reg = 0; reg < 4; ++reg) al2[reg] = aS[wave * 16 + quad * 4 + reg];
#pragma unroll
            for (int ni = 0; ni < 8; ++ni)
#pragma unroll
                for (int reg = 0; reg < 4; ++reg) o_acc[ni][reg] *= al2[reg];
#pragma unroll
            for (int ks = 0; ks < 2; ++ks) {
                bf16x8 a = *(const bf16x8*)&Ps2[(wave * 16 + l16) * 64 + ks * 32 + quad * 8];
#pragma unroll
                for (int ni = 0; ni < 8; ++ni) {
                    bf16x8 b = *(const bf16x8*)&Vt2[(ni * 16 + l16) * 80 + ks * 32 + quad * 8];
                    o_acc[ni] = __builtin_amdgcn_mfma_f32_16x16x32_bf16(a, b, o_acc[ni], 0, 0, 0);
                }
            }
        }
        __syncthreads();
    }
    {
        float linv[4];
#pragma unroll
        for (int reg = 0; reg < 4; ++reg) linv[reg] = 1.f / fmaxf(lS[wave * 16 + quad * 4 + reg], 1e-20f);
#pragma unroll
        for (int ni = 0; ni < 8; ++ni)
#pragma unroll
            for (int reg = 0; reg < 4; ++reg) {
                int r = wave * 16 + quad * 4 + reg;
                obuf[(size_t)(qi * 64 + r) * HID + hh * HD + ni * 16 + l16] = (bf16)(o_acc[ni][reg] * linv[reg]);
            }
    }
}

// ---------------------------------------------------------------------------
extern "C" void kernel_launch(void* const* d_in, const int* in_sizes, int n_in,
                              void* d_out, int out_size, void* d_ws, size_t ws_size,
                              hipStream_t stream) {
    const float* x   = (const float*)d_in[0];
    const float* Wq  = (const float*)d_in[1];
    const float* bq  = (const float*)d_in[2];
    const float* Wk  = (const float*)d_in[3];
    const float* bk  = (const float*)d_in[4];
    const float* Wv  = (const float*)d_in[5];
    const float* bv  = (const float*)d_in[6];
    const float* Wo  = (const float*)d_in[7];
    const float* bo  = (const float*)d_in[8];
    const float* qg  = (const float*)d_in[9];
    const float* qbt = (const float*)d_in[10];
    const float* kg  = (const float*)d_in[11];
    const float* kbt = (const float*)d_in[12];
    float* out = (float*)d_out;

    // fast-path workspace layout (130,547,712 B):
    //   [0, 64MiB)           : xb (16MiB) | Wqkv (48MiB)   -- later aliased by OP (fp32 x2)
    //   [64MiB, 96MiB)       : Wob
    //   [96MiB, 120MiB)      : qkv (24MiB)                 -- later aliased by abuf (16MiB)
    //   [120MiB, 124MiB)     : vT
    //   [124MiB, +512KiB)    : lbuf
    const size_t NEED = 130547712;
    if (ws_size >= NEED) {
        char* p = (char*)d_ws;
        bf16*  xb   = (bf16*)p;
        bf16*  Wqkv = (bf16*)(p + 16777216);
        float* OP   = (float*)p;                       // aliases xb+Wqkv (both dead by attn)
        bf16*  Wob  = (bf16*)(p + 67108864);
        bf16*  qkv  = (bf16*)(p + 100663296);
        bf16*  abuf = (bf16*)(p + 100663296);          // aliases qkv (dead after attn)
        bf16*  vT   = (bf16*)(p + 125829120);
        float* lbuf = (float*)(p + 130023424);

        // fp32 -> bf16: x and packed W_qkv rows [Wq | Wk | Wv], plus Wo
        cvt<<<4096, 256, 0, stream>>>(x,  xb, 1048576);
        cvt<<<8192, 256, 0, stream>>>(Wq, Wqkv, 2097152);
        cvt<<<2048, 256, 0, stream>>>(Wk, Wqkv + (size_t)4096 * 4096, 524288);
        cvt<<<2048, 256, 0, stream>>>(Wv, Wqkv + (size_t)5120 * 4096, 524288);
        cvt<<<8192, 256, 0, stream>>>(Wo, Wob, 2097152);

        // fused QKV projection: [2048 x 6144], 256x256 tiles, pipelined
        gemm_p<256, 256, 2, 4, 1, bf16><<<dim3(24, 8), 512, 0, stream>>>(
            xb, Wqkv, bq, bk, bv, qkv, QSTR, 4096);

        // LN + RoPE in place (q pre-scaled by QSCL)
        ln_rope<<<dim3((S_LEN * (NH + NKV)) / 4), 256, 0, stream>>>(qkv, qg, qbt, kg, kbt);

        // v -> vT
        transpose_v<<<dim3(16, 32), 256, 0, stream>>>(qkv, vT);

        // balanced split-K attention -> fp32 partials, then merge
        attn3<<<dim3(64, 8), 256, 0, stream>>>(qkv, vT, OP, lbuf);
        merge<<<8192, 256, 0, stream>>>(OP, lbuf, abuf);

        // output projection: 256x128 tiles (full 256-block grid), pipelined
        gemm_p<256, 128, 4, 2, 0, float><<<dim3(32, 8), 512, 0, stream>>>(
            abuf, Wob, bo, bo, bo, out, 4096, 4096);
    } else {
        char* ws = (char*)d_ws;
        bf16* qbuf = (bf16*)(ws);
        bf16* kbuf = (bf16*)(ws + (16u << 20));
        bf16* vbuf = (bf16*)(ws + (20u << 20));
        bf16* abuf = (bf16*)(ws + (24u << 20));
        gemm_bt<float, bf16><<<dim3(32, 16), 256, 0, stream>>>(x, Wq, bq, qbuf, 4096, 4096);
        gemm_bt<float, bf16><<<dim3(8, 16), 256, 0, stream>>>(x, Wk, bk, kbuf, 1024, 4096);
        gemm_bt<float, bf16><<<dim3(8, 16), 256, 0, stream>>>(x, Wv, bv, vbuf, 1024, 4096);
        ln_rope_f<<<dim3((S_LEN * (NH + NKV)) / 4), 256, 0, stream>>>(qbuf, kbuf, qg, qbt, kg, kbt);
        attn_old<<<dim3(32, 32), 256, 0, stream>>>(qbuf, kbuf, vbuf, abuf);
        gemm_bt<bf16, float><<<dim3(32, 16), 256, 0, stream>>>(abuf, Wo, bo, out, 4096, 4096);
    }
}

// Round 2
// 578.438 us; speedup vs baseline: 1.2013x; 1.1756x over previous
//
#include <hip/hip_runtime.h>

typedef __bf16 bf16;
typedef __bf16 bf16x8 __attribute__((ext_vector_type(8)));
typedef __bf16 bf16x4 __attribute__((ext_vector_type(4)));
typedef float f32x4 __attribute__((ext_vector_type(4)));

#define S_LEN 2048
#define HID 4096
#define NH 32
#define NKV 8
#define HD 128
#define QSTR 6144                      // fused qkv row stride
#define SCALE 0.08838834764831845f
#define QSCL 0.1275164918918885f       // SCALE * log2(e)
#define M2C 16.33f                     // >= 128*QSCL = 16.3221 (Cauchy-Schwarz hard bound)

template <int V> struct IC { static constexpr int value = V; };

__device__ __forceinline__ bf16x8 load8(const bf16* p) { return *(const bf16x8*)p; }
__device__ __forceinline__ bf16x8 load8(const float* p) {
    float4 a = *(const float4*)p;
    float4 b = *(const float4*)(p + 4);
    bf16x8 r;
    r[0] = (bf16)a.x; r[1] = (bf16)a.y; r[2] = (bf16)a.z; r[3] = (bf16)a.w;
    r[4] = (bf16)b.x; r[5] = (bf16)b.y; r[6] = (bf16)b.z; r[7] = (bf16)b.w;
    return r;
}

__device__ __forceinline__ void load_lds16(const bf16* g, bf16* l) {
    __builtin_amdgcn_global_load_lds(
        (const __attribute__((address_space(1))) void*)g,
        (__attribute__((address_space(3))) void*)l, 16, 0, 0);
}

template <int C> __device__ __forceinline__ void vmwait_if() {
    if constexpr (C >= 0) asm volatile("s_waitcnt vmcnt(%0)" ::"n"(C) : "memory");
}

__device__ __forceinline__ void lgkm0() {
    asm volatile("s_waitcnt lgkmcnt(0)" ::: "memory");
    __builtin_amdgcn_sched_barrier(0);
}

// ---------------------------------------------------------------------------
// fp32 -> bf16 bulk convert
// ---------------------------------------------------------------------------
__global__ __launch_bounds__(256) void cvt(const float* __restrict__ in,
                                           bf16* __restrict__ out, int n8) {
    int i = blockIdx.x * 256 + threadIdx.x;
    if (i < n8) *(bf16x8*)&out[i * 8] = load8(&in[(size_t)i * 8]);
}

// ---------------------------------------------------------------------------
// 8-phase pipelined GEMM (m201-style): out[M,N] = A[M,K] @ B[N,K]^T + bias.
// BK=64, double-buffered LDS; A split into 2 mi-half chunks, B into 2 ni-half
// chunks. Per K-tile: 4 phases {ds_read subtile | stage 1 chunk | barrier |
// lgkmcnt(0) | setprio(1) MFMA setprio(0) | barrier}, counted vmcnt twice per
// K-tile (never 0 in steady state). A/B fragments register-cached across the
// phases that reuse them. Granule-XOR swizzle: linear LDS dest (gload_lds),
// inverse-swizzled global source, swizzled ds_read -> 0 bank conflicts.
// 8 waves (WM x WN). BMODE 0: bias=b0[n]. BMODE 1: packed-QKV bias.
// Requires K % 64 == 0, K/64 >= 3, full tiles.
// ---------------------------------------------------------------------------
template <int BM, int BN, int WM, int WN, int BMODE, typename TO>
__global__ __launch_bounds__(512, 2) void gemm8(const bf16* __restrict__ A,
                                                const bf16* __restrict__ Bw,
                                                const float* __restrict__ b0,
                                                const float* __restrict__ b1,
                                                const float* __restrict__ b2,
                                                TO* __restrict__ out,
                                                int N, int K) {
    constexpr int RW  = BM / WM;           // rows per wave
    constexpr int CW  = BN / WN;           // cols per wave
    constexpr int FM  = RW / 16;           // m fragments per wave
    constexpr int FN  = CW / 16;           // n fragments per wave
    constexpr int FMH = FM / 2;            // m fragments per mi-half
    constexpr int FNH0 = (FN + 1) / 2, FNH1 = FN - FNH0;
    constexpr int SZ0 = FNH0 * 16, SZ1 = FNH1 * 16;   // per-wave rows per B chunk
    constexpr int AROWS_H = BM / 2;                    // rows per A chunk
    constexpr int B0ROWS = WN * SZ0, B1ROWS = WN * SZ1;
    constexpr int LA  = AROWS_H / 64;      // gload_lds per thread per A chunk
    constexpr int LB0 = B0ROWS / 64, LB1 = B1ROWS / 64;
    // vmcnt schedule (derived from issue timeline; see prologue/loop order):
    constexpr int V0  = 2 * LA + LB0;            // end of phase 0
    constexpr int V3  = 2 * LA + LB0 + LB1;      // end of phase 3 (= prologue)
    constexpr int V3T = LA + LB1;                // end of phase 3, tile NT-2

    __shared__ __align__(16) bf16 AS[2 * BM * 64];
    __shared__ __align__(16) bf16 BS[2 * BN * 64];

    const int tid  = threadIdx.x;
    const int wave = tid >> 6;
    const int lane = tid & 63;
    const int quad = lane >> 4;
    const int l16  = lane & 15;
    const int wm   = wave / WN;
    const int wn   = wave % WN;

    // XCD-aware swizzle: 256 blocks -> each XCD owns one contiguous row-panel
    const int gx   = gridDim.x;
    const int nwg  = gx * gridDim.y;
    const int orig = blockIdx.y * gx + blockIdx.x;
    int wg = orig;
    if ((nwg & 7) == 0) wg = (orig & 7) * (nwg >> 3) + (orig >> 3);
    const int row0 = (wg / gx) * BM;
    const int col0 = (wg % gx) * BN;

    auto stageA = [&](int mh, int bufv, int kt) {
#pragma unroll
        for (int j = 0; j < LA; ++j) {
            int c = j * 512 + tid;
            int r = c >> 3, pg = c & 7;
            int g = pg ^ (r & 7);                           // inverse-swizzled src granule
            int gr = (r / (RW / 2)) * RW + mh * (RW / 2) + (r % (RW / 2));
            load_lds16(&A[(size_t)(row0 + gr) * K + kt * 64 + g * 8],
                       &AS[bufv * (BM * 64) + mh * (AROWS_H * 64) + c * 8]);
        }
    };
    auto stageB0 = [&](int bufv, int kt) {
#pragma unroll
        for (int j = 0; j < LB0; ++j) {
            int c = j * 512 + tid;
            int r = c >> 3, pg = c & 7;
            int g = pg ^ (r & 7);
            int gc = (r / SZ0) * CW + (r % SZ0);
            load_lds16(&Bw[(size_t)(col0 + gc) * K + kt * 64 + g * 8],
                       &BS[bufv * (BN * 64) + c * 8]);
        }
    };
    auto stageB1 = [&](int bufv, int kt) {
#pragma unroll
        for (int j = 0; j < LB1; ++j) {
            int c = j * 512 + tid;
            int r = c >> 3, pg = c & 7;
            int g = pg ^ (r & 7);
            int gc = (r / SZ1) * CW + SZ0 + (r % SZ1);
            load_lds16(&Bw[(size_t)(col0 + gc) * K + kt * 64 + g * 8],
                       &BS[bufv * (BN * 64) + B0ROWS * 64 + c * 8]);
        }
    };

    f32x4 acc[FM][FN];
#pragma unroll
    for (int mi = 0; mi < FM; ++mi)
#pragma unroll
        for (int ni = 0; ni < FN; ++ni) { f32x4 z = {0.f, 0.f, 0.f, 0.f}; acc[mi][ni] = z; }

    bf16x8 af[FMH][2];      // current mi-half's A fragments (reused across 2 phases)
    bf16x8 bfv[FN][2];      // all B fragments of the tile (reused across mi-halves)

    auto loadA = [&](int mh, int bufv) {
#pragma unroll
        for (int mi = 0; mi < FMH; ++mi)
#pragma unroll
            for (int ks = 0; ks < 2; ++ks) {
                int r = wm * (RW / 2) + mi * 16 + l16;
                int g = ks * 4 + quad;
                af[mi][ks] = *(const bf16x8*)&AS[bufv * (BM * 64) + mh * (AROWS_H * 64) +
                                                 r * 64 + ((g ^ (r & 7)) << 3)];
            }
    };
    auto loadB = [&](auto cNH, int bufv) {
        constexpr int NHv = decltype(cNH)::value;
        constexpr int CNT = NHv ? FNH1 : FNH0;
        constexpr int SZ  = NHv ? SZ1 : SZ0;
#pragma unroll
        for (int nj = 0; nj < CNT; ++nj)
#pragma unroll
            for (int ks = 0; ks < 2; ++ks) {
                int r = wn * SZ + nj * 16 + l16;
                int g = ks * 4 + quad;
                bfv[NHv * FNH0 + nj][ks] =
                    *(const bf16x8*)&BS[bufv * (BN * 64) + NHv * (B0ROWS * 64) +
                                        r * 64 + ((g ^ (r & 7)) << 3)];
            }
    };
    auto mmac = [&](auto cMH, auto cNH) {
        constexpr int MH = decltype(cMH)::value, NHv = decltype(cNH)::value;
        constexpr int NB = NHv ? FNH0 : 0, NE = NHv ? FN : FNH0;
        __builtin_amdgcn_s_setprio(1);
#pragma unroll
        for (int mi = 0; mi < FMH; ++mi)
#pragma unroll
            for (int ni = NB; ni < NE; ++ni)
#pragma unroll
                for (int ks = 0; ks < 2; ++ks)
                    acc[MH * FMH + mi][ni] = __builtin_amdgcn_mfma_f32_16x16x32_bf16(
                        af[mi][ks], bfv[ni][ks], acc[MH * FMH + mi][ni], 0, 0, 0);
        __builtin_amdgcn_s_setprio(0);
    };

    // K-tile body. Stage schedule: p0 -> A1(t+1), p1 -> B1(t+1),
    // p2 -> A0(t+2), p3 -> B0(t+2). Each target chunk freed >=1 phase earlier.
    auto run_tile = [&](int t, auto cSA1, auto cSB1, auto cSA0, auto cSB0,
                        auto cV0, auto cV3) {
        const int buf = t & 1, nbuf = buf ^ 1;
        // phase (mh0, nh0)
        loadA(0, buf);
        loadB(IC<0>{}, buf);
        if constexpr (decltype(cSA1)::value) stageA(1, nbuf, t + 1);
        __builtin_amdgcn_s_barrier();
        lgkm0();
        mmac(IC<0>{}, IC<0>{});
        vmwait_if<decltype(cV0)::value>();
        __builtin_amdgcn_s_barrier();
        // phase (mh0, nh1)
        loadB(IC<1>{}, buf);
        if constexpr (decltype(cSB1)::value) stageB1(nbuf, t + 1);
        __builtin_amdgcn_s_barrier();
        lgkm0();
        mmac(IC<0>{}, IC<1>{});
        __builtin_amdgcn_s_barrier();
        // phase (mh1, nh0)
        loadA(1, buf);
        if constexpr (decltype(cSA0)::value) stageA(0, buf, t + 2);
        __builtin_amdgcn_s_barrier();
        lgkm0();
        mmac(IC<1>{}, IC<0>{});
        __builtin_amdgcn_s_barrier();
        // phase (mh1, nh1)
        if constexpr (decltype(cSB0)::value) stageB0(buf, t + 2);
        __builtin_amdgcn_s_barrier();
        lgkm0();
        mmac(IC<1>{}, IC<1>{});
        vmwait_if<decltype(cV3)::value>();
        __builtin_amdgcn_s_barrier();
    };

    // prologue: A0(0) B0(0) A1(0) B1(0) A0(1) B0(1); wait tile0's A0/B0.
    stageA(0, 0, 0); stageB0(0, 0);
    stageA(1, 0, 0); stageB1(0, 0);
    stageA(0, 1, 1); stageB0(1, 1);
    vmwait_if<V3>();
    __builtin_amdgcn_s_barrier();

    const int NT = K >> 6;
    for (int t = 0; t < NT - 2; ++t)
        run_tile(t, IC<1>{}, IC<1>{}, IC<1>{}, IC<1>{}, IC<V0>{}, IC<V3>{});
    run_tile(NT - 2, IC<1>{}, IC<1>{}, IC<0>{}, IC<0>{}, IC<V0>{}, IC<V3T>{});
    run_tile(NT - 1, IC<0>{}, IC<0>{}, IC<0>{}, IC<0>{}, IC<0>{}, IC<-1>{});

#pragma unroll
    for (int ni = 0; ni < FN; ++ni) {
        int n = col0 + wn * CW + ni * 16 + l16;
        float bv;
        if (BMODE == 0) bv = b0[n];
        else bv = (n < 4096) ? b0[n] : ((n < 5120) ? b1[n - 4096] : b2[n - 5120]);
#pragma unroll
        for (int mi = 0; mi < FM; ++mi) {
            int m = row0 + wm * RW + mi * 16 + quad * 4;
#pragma unroll
            for (int reg = 0; reg < 4; ++reg)
                out[(size_t)(m + reg) * N + n] = (TO)(acc[mi][ni][reg] + bv);
        }
    }
}

// ---------------------------------------------------------------------------
// LayerNorm(HD=128) + RoPE in place on fused qkv buffer (stride QSTR).
// q rows additionally pre-scaled by QSCL (softmax works in log2 domain).
// ---------------------------------------------------------------------------
__global__ __launch_bounds__(256) void ln_rope(bf16* __restrict__ qkv,
                                               const float* __restrict__ qg, const float* __restrict__ qbt,
                                               const float* __restrict__ kg, const float* __restrict__ kbt) {
    int row  = blockIdx.x * 4 + (threadIdx.x >> 6);
    int lane = threadIdx.x & 63;

    bf16* ptr;
    const float *g, *bb;
    int s;
    float osc;
    if (row < S_LEN * NH) {
        s   = row >> 5;
        ptr = qkv + (size_t)s * QSTR + (row & 31) * HD;
        g   = qg; bb = qbt; osc = QSCL;
    } else {
        int r2 = row - S_LEN * NH;
        s   = r2 >> 3;
        ptr = qkv + (size_t)s * QSTR + 4096 + (r2 & 7) * HD;
        g   = kg; bb = kbt; osc = 1.f;
    }

    float x1 = (float)ptr[lane];
    float x2 = (float)ptr[lane + 64];
    float sum = x1 + x2;
    float sq  = x1 * x1 + x2 * x2;
#pragma unroll
    for (int m = 1; m < 64; m <<= 1) {
        sum += __shfl_xor(sum, m);
        sq  += __shfl_xor(sq, m);
    }
    float mu  = sum * (1.f / 128.f);
    float var = sq * (1.f / 128.f) - mu * mu;
    float rs  = rsqrtf(var + 1e-5f);
    float n1  = (x1 - mu) * rs * g[lane] + bb[lane];
    float n2  = (x2 - mu) * rs * g[lane + 64] + bb[lane + 64];

    float inv = powf(500000.f, -(float)lane * (1.f / 64.f));
    float ang = (float)s * inv;
    float sn, cs;
    sincosf(ang, &sn, &cs);

    ptr[lane]      = (bf16)((n1 * cs - n2 * sn) * osc);
    ptr[lane + 64] = (bf16)((n2 * cs + n1 * sn) * osc);
}

// ---------------------------------------------------------------------------
// Transpose v (cols 5120..6143 of qkv, [s][c]) -> vT [c][s]. 64x64 LDS tiles,
// XOR-swizzled (write b128 free; read 8xb16 2-way = free).
// ---------------------------------------------------------------------------
__global__ __launch_bounds__(256) void transpose_v(const bf16* __restrict__ qkv,
                                                   bf16* __restrict__ vT) {
    __shared__ bf16 Ts[64 * 64];
    const int c0 = blockIdx.x * 64;
    const int s0 = blockIdx.y * 64;
    const int tid = threadIdx.x;

#pragma unroll
    for (int i = 0; i < 2; ++i) {
        int cc = i * 256 + tid;
        int r = cc >> 3, col8 = cc & 7;
        *(bf16x8*)&Ts[r * 64 + ((col8 ^ (r & 7)) << 3)] =
            *(const bf16x8*)&qkv[(size_t)(s0 + r) * QSTR + 5120 + c0 + (col8 << 3)];
    }
    __syncthreads();
#pragma unroll
    for (int i = 0; i < 2; ++i) {
        int oc = i * 256 + tid;
        int c = oc & 63, sb = oc >> 6;
        bf16x8 r8;
#pragma unroll
        for (int j = 0; j < 8; ++j) {
            int sg = sb * 8 + j;
            r8[j] = Ts[sg * 64 + ((((c >> 3) ^ (sg & 7)) << 3) + (c & 7))];
        }
        *(bf16x8*)&vT[(size_t)(c0 + c) * S_LEN + s0 + sb * 8] = r8;
    }
}

// ---------------------------------------------------------------------------
// Flash attention v3: fixed-max softmax (log2 domain), balanced split-K.
// Block = (pair p, split sp, kvh). Processes Q-tiles p and 63-p (32 rows),
// K-tiles kt == sp (mod 2). Wave w owns head kvh*4+w. Register-prefetched
// staging. Row sums via MFMA ones-trick. Writes fp32 partials OP[sp] + l.
// ---------------------------------------------------------------------------
__global__ __launch_bounds__(256, 2) void attn3(const bf16* __restrict__ qkv,
                                                const bf16* __restrict__ vT,
                                                float* __restrict__ OP,
                                                float* __restrict__ lbuf) {
    const int pairp = blockIdx.x >> 1;
    const int sp    = blockIdx.x & 1;
    const int kvh   = blockIdx.y;
    const int tid   = threadIdx.x;
    const int wave  = tid >> 6;
    const int lane  = tid & 63;
    const int quad  = lane >> 4;
    const int l16   = lane & 15;
    const int h     = kvh * 4 + wave;

    __shared__ __align__(16) bf16 Ks[64 * 128];
    __shared__ __align__(16) bf16 Vt[128 * 64];
    __shared__ __align__(16) bf16 Ps[4][32 * 64];

    float* OPs = OP + (size_t)sp * (S_LEN * HID);
    float* lbs = lbuf + sp * (S_LEN * NH);

    bf16x8 onesf;
#pragma unroll
    for (int j = 0; j < 8; ++j) onesf[j] = (bf16)1.f;

    int4 pk[4], pv[4];

    for (int ph = 0; ph < 2; ++ph) {
        const int qt  = ph ? (63 - pairp) : pairp;
        const int r0  = qt * 32;
        const int nkt = qt / 2 + 1;
        const int nit = (nkt + 1 - sp) / 2;   // kt = sp + 2*it < nkt

        // Q fragments (already scaled by QSCL in ln_rope)
        bf16x8 qf[2][4];
#pragma unroll
        for (int mi = 0; mi < 2; ++mi)
#pragma unroll
            for (int ks = 0; ks < 4; ++ks)
                qf[mi][ks] = *(const bf16x8*)&qkv[(size_t)(r0 + mi * 16 + l16) * QSTR +
                                                  h * HD + ks * 32 + quad * 8];

        f32x4 o_acc[2][8];
#pragma unroll
        for (int mi = 0; mi < 2; ++mi)
#pragma unroll
            for (int ni = 0; ni < 8; ++ni) {
                f32x4 z = {0.f, 0.f, 0.f, 0.f};
                o_acc[mi][ni] = z;
            }
        f32x4 lacc[2];
#pragma unroll
        for (int mi = 0; mi < 2; ++mi) { f32x4 z = {0.f, 0.f, 0.f, 0.f}; lacc[mi] = z; }

        auto load_regs = [&](int kt) {
#pragma unroll
            for (int i = 0; i < 4; ++i) {
                int cc = i * 256 + tid;
                int key = cc >> 4, d8 = cc & 15;
                pk[i] = *(const int4*)&qkv[(size_t)(kt * 64 + key) * QSTR + 4096 +
                                           kvh * HD + (d8 << 3)];
            }
#pragma unroll
            for (int i = 0; i < 4; ++i) {
                int cc = i * 256 + tid;
                int d = cc >> 3, k8 = cc & 7;
                pv[i] = *(const int4*)&vT[(size_t)(kvh * HD + d) * S_LEN + kt * 64 + (k8 << 3)];
            }
        };

        if (nit > 0) load_regs(sp);

        for (int it = 0; it < nit; ++it) {
            const int kt = sp + 2 * it;
            // drain prefetch regs into swizzled LDS
#pragma unroll
            for (int i = 0; i < 4; ++i) {
                int cc = i * 256 + tid;
                int key = cc >> 4, d8 = cc & 15;
                *(int4*)&Ks[key * 128 + ((d8 ^ (key & 7)) << 3)] = pk[i];
            }
#pragma unroll
            for (int i = 0; i < 4; ++i) {
                int cc = i * 256 + tid;
                int d = cc >> 3, k8 = cc & 7;
                *(int4*)&Vt[d * 64 + ((k8 ^ (d & 7)) << 3)] = pv[i];
            }
            __syncthreads();

            if (it + 1 < nit) load_regs(kt + 2);   // prefetch next tile

            // S = Q K^T (log2-scaled)
            f32x4 sacc[2][4];
#pragma unroll
            for (int mi = 0; mi < 2; ++mi)
#pragma unroll
                for (int ni = 0; ni < 4; ++ni) {
                    f32x4 z = {0.f, 0.f, 0.f, 0.f};
                    sacc[mi][ni] = z;
                }
#pragma unroll
            for (int ks = 0; ks < 4; ++ks)
#pragma unroll
                for (int ni = 0; ni < 4; ++ni) {
                    bf16x8 kf = *(const bf16x8*)&Ks[(ni * 16 + l16) * 128 +
                                                    ((((ks << 2) + quad) ^ (l16 & 7)) << 3)];
                    sacc[0][ni] = __builtin_amdgcn_mfma_f32_16x16x32_bf16(qf[0][ks], kf, sacc[0][ni], 0, 0, 0);
                    sacc[1][ni] = __builtin_amdgcn_mfma_f32_16x16x32_bf16(qf[1][ks], kf, sacc[1][ni], 0, 0, 0);
                }

            // fixed-max softmax: p = exp2(s2 - M2C); masked -> 0
#pragma unroll
            for (int mi = 0; mi < 2; ++mi)
#pragma unroll
                for (int reg = 0; reg < 4; ++reg) {
                    int rloc = mi * 16 + quad * 4 + reg;
                    int qrow = r0 + rloc;
#pragma unroll
                    for (int ni = 0; ni < 4; ++ni) {
                        int key = kt * 64 + ni * 16 + l16;
                        float t = (key > qrow) ? -1e30f : (sacc[mi][ni][reg] - M2C);
                        float p = exp2f(t);
                        int blk = (ni * 2 + (l16 >> 3)) ^ (rloc & 7);
                        Ps[wave][rloc * 64 + blk * 8 + (l16 & 7)] = (bf16)p;
                    }
                }

            // O += P @ V ; l += P @ ones  (per-wave Ps: no barrier needed)
#pragma unroll
            for (int ks2 = 0; ks2 < 2; ++ks2) {
                bf16x8 pa[2];
#pragma unroll
                for (int mi = 0; mi < 2; ++mi) {
                    int rloc = mi * 16 + l16;
                    pa[mi] = *(const bf16x8*)&Ps[wave][rloc * 64 +
                                                       ((((ks2 << 2) + quad) ^ (rloc & 7)) << 3)];
                }
#pragma unroll
                for (int ni = 0; ni < 8; ++ni) {
                    int d = ni * 16 + l16;
                    bf16x8 vf = *(const bf16x8*)&Vt[d * 64 + ((((ks2 << 2) + quad) ^ (d & 7)) << 3)];
                    o_acc[0][ni] = __builtin_amdgcn_mfma_f32_16x16x32_bf16(pa[0], vf, o_acc[0][ni], 0, 0, 0);
                    o_acc[1][ni] = __builtin_amdgcn_mfma_f32_16x16x32_bf16(pa[1], vf, o_acc[1][ni], 0, 0, 0);
                }
                lacc[0] = __builtin_amdgcn_mfma_f32_16x16x32_bf16(pa[0], onesf, lacc[0], 0, 0, 0);
                lacc[1] = __builtin_amdgcn_mfma_f32_16x16x32_bf16(pa[1], onesf, lacc[1], 0, 0, 0);
            }
            __syncthreads();
        }

        // partial epilogue (always runs; zeros if nit==0)
#pragma unroll
        for (int mi = 0; mi < 2; ++mi)
#pragma unroll
            for (int reg = 0; reg < 4; ++reg) {
                int s = r0 + mi * 16 + quad * 4 + reg;
#pragma unroll
                for (int ni = 0; ni < 8; ++ni)
                    OPs[(size_t)s * HID + h * HD + ni * 16 + l16] = o_acc[mi][ni][reg];
                if (l16 == 0) lbs[s * NH + h] = lacc[mi][reg];
            }
    }
}

// ---------------------------------------------------------------------------
// merge: abuf[s][h*128+d] = (OP0 + OP1) / (l0 + l1)
// ---------------------------------------------------------------------------
__global__ __launch_bounds__(256) void merge(const float* __restrict__ OP,
                                             const float* __restrict__ lb,
                                             bf16* __restrict__ abuf) {
    int g = blockIdx.x * 256 + threadIdx.x;      // 0 .. 2048*1024-1
    int s = g >> 10;
    int col = (g & 1023) << 2;
    int h = col >> 7;
    float l = lb[s * NH + h] + lb[S_LEN * NH + s * NH + h];
    float inv = 1.f / fmaxf(l, 1e-30f);
    f32x4 o0 = *(const f32x4*)&OP[(size_t)g << 2];
    f32x4 o1 = *(const f32x4*)&OP[((size_t)g << 2) + (size_t)S_LEN * HID];
    bf16x4 r;
#pragma unroll
    for (int j = 0; j < 4; ++j) r[j] = (bf16)((o0[j] + o1[j]) * inv);
    *(bf16x4*)&abuf[(size_t)s * HID + col] = r;
}

// ===========================================================================
// Fallback path (round-3, proven) — only if workspace is unexpectedly small.
// ===========================================================================
template <typename TA, typename TO>
__global__ __launch_bounds__(256) void gemm_bt(const TA* __restrict__ A,
                                               const float* __restrict__ W,
                                               const float* __restrict__ bias,
                                               TO* __restrict__ out,
                                               int N, int K) {
    __shared__ __align__(16) bf16 As[128 * 64];
    __shared__ __align__(16) bf16 Bs[128 * 64];
    const int tid = threadIdx.x, wave = tid >> 6, lane = tid & 63;
    const int quad = lane >> 4, l16 = lane & 15, wm = wave >> 1, wn = wave & 1;
    const int row0 = blockIdx.y * 128, col0 = blockIdx.x * 128;
    f32x4 acc[4][4];
#pragma unroll
    for (int mi = 0; mi < 4; ++mi)
#pragma unroll
        for (int ni = 0; ni < 4; ++ni) { f32x4 z = {0.f,0.f,0.f,0.f}; acc[mi][ni] = z; }
    for (int k0 = 0; k0 < K; k0 += 64) {
#pragma unroll
        for (int i = 0; i < 4; ++i) {
            int c = i * 256 + tid, r = c >> 3, col8 = (c & 7) << 3;
            *(bf16x8*)&As[r * 64 + col8] = load8(&A[(size_t)(row0 + r) * K + k0 + col8]);
            *(bf16x8*)&Bs[r * 64 + col8] = load8(&W[(size_t)(col0 + r) * K + k0 + col8]);
        }
        __syncthreads();
#pragma unroll
        for (int ks = 0; ks < 2; ++ks) {
            bf16x8 af[4], bfr[4];
#pragma unroll
            for (int mi = 0; mi < 4; ++mi)
                af[mi] = *(const bf16x8*)&As[(wm * 64 + mi * 16 + l16) * 64 + ks * 32 + quad * 8];
#pragma unroll
            for (int ni = 0; ni < 4; ++ni)
                bfr[ni] = *(const bf16x8*)&Bs[(wn * 64 + ni * 16 + l16) * 64 + ks * 32 + quad * 8];
#pragma unroll
            for (int mi = 0; mi < 4; ++mi)
#pragma unroll
                for (int ni = 0; ni < 4; ++ni)
                    acc[mi][ni] = __builtin_amdgcn_mfma_f32_16x16x32_bf16(af[mi], bfr[ni], acc[mi][ni], 0, 0, 0);
        }
        __syncthreads();
    }
#pragma unroll
    for (int ni = 0; ni < 4; ++ni) {
        int n = col0 + wn * 64 + ni * 16 + l16;
        float bv = bias[n];
#pragma unroll
        for (int mi = 0; mi < 4; ++mi) {
            int m = row0 + wm * 64 + mi * 16 + quad * 4;
#pragma unroll
            for (int reg = 0; reg < 4; ++reg)
                out[(size_t)(m + reg) * N + n] = (TO)(acc[mi][ni][reg] + bv);
        }
    }
}

__global__ __launch_bounds__(256) void ln_rope_f(bf16* __restrict__ qb, bf16* __restrict__ kb,
                                                 const float* __restrict__ qg, const float* __restrict__ qbt,
                                                 const float* __restrict__ kg, const float* __restrict__ kbt) {
    int row = blockIdx.x * 4 + (threadIdx.x >> 6);
    int lane = threadIdx.x & 63;
    bf16* ptr; const float *g, *bb; int s;
    if (row < S_LEN * NH) { s = row >> 5; ptr = qb + (size_t)s * (NH * HD) + (row & 31) * HD; g = qg; bb = qbt; }
    else { int r2 = row - S_LEN * NH; s = r2 >> 3; ptr = kb + (size_t)s * (NKV * HD) + (r2 & 7) * HD; g = kg; bb = kbt; }
    float x1 = (float)ptr[lane], x2 = (float)ptr[lane + 64];
    float sum = x1 + x2, sq = x1 * x1 + x2 * x2;
#pragma unroll
    for (int m = 1; m < 64; m <<= 1) { sum += __shfl_xor(sum, m); sq += __shfl_xor(sq, m); }
    float mu = sum * (1.f / 128.f), var = sq * (1.f / 128.f) - mu * mu;
    float rs = rsqrtf(var + 1e-5f);
    float n1 = (x1 - mu) * rs * g[lane] + bb[lane];
    float n2 = (x2 - mu) * rs * g[lane + 64] + bb[lane + 64];
    float inv = powf(500000.f, -(float)lane * (1.f / 64.f));
    float ang = (float)s * inv, sn, cs;
    sincosf(ang, &sn, &cs);
    ptr[lane] = (bf16)(n1 * cs - n2 * sn);
    ptr[lane + 64] = (bf16)(n2 * cs + n1 * sn);
}

__global__ __launch_bounds__(256) void attn_old(const bf16* __restrict__ qbuf,
                                                const bf16* __restrict__ kbuf,
                                                const bf16* __restrict__ vbuf,
                                                bf16* __restrict__ obuf) {
    const int qi = blockIdx.x, hh = blockIdx.y, kvh = hh >> 2;
    __shared__ __align__(16) bf16 Qs[64 * 128];
    __shared__ __align__(16) bf16 Ks2[64 * 128];
    __shared__ __align__(16) bf16 Vt2[128 * 80];
    __shared__ __align__(16) float Ss[64 * 64];
    __shared__ __align__(16) bf16 Ps2[64 * 64];
    __shared__ float mS[64], lS[64], aS[64];
    const int tid = threadIdx.x, wave = tid >> 6, lane = tid & 63;
    const int quad = lane >> 4, l16 = lane & 15;
#pragma unroll
    for (int i = 0; i < 4; ++i) {
        int c = i * 256 + tid, r = c >> 4, col8 = (c & 15) << 3;
        *(int4*)&Qs[r * 128 + col8] = *(const int4*)&qbuf[(size_t)(qi * 64 + r) * HID + hh * HD + col8];
    }
    if (tid < 64) { mS[tid] = -1e30f; lS[tid] = 0.f; }
    f32x4 o_acc[8];
#pragma unroll
    for (int i = 0; i < 8; ++i) { f32x4 z = {0.f,0.f,0.f,0.f}; o_acc[i] = z; }
    __syncthreads();
    for (int kt = 0; kt <= qi; ++kt) {
#pragma unroll
        for (int i = 0; i < 4; ++i) {
            int c = i * 256 + tid, r = c >> 4, col8 = (c & 15) << 3;
            const size_t gofs = (size_t)(kt * 64 + r) * (NKV * HD) + kvh * HD + col8;
            *(int4*)&Ks2[r * 128 + col8] = *(const int4*)&kbuf[gofs];
            bf16x8 vv = *(const bf16x8*)&vbuf[gofs];
#pragma unroll
            for (int e = 0; e < 8; ++e) Vt2[(col8 + e) * 80 + r] = vv[e];
        }
        __syncthreads();
        f32x4 sacc[4];
#pragma unroll
        for (int ni = 0; ni < 4; ++ni) { f32x4 z = {0.f,0.f,0.f,0.f}; sacc[ni] = z; }
#pragma unroll
        for (int ks = 0; ks < 4; ++ks) {
            bf16x8 a = *(const bf16x8*)&Qs[(wave * 16 + l16) * 128 + ks * 32 + quad * 8];
#pragma unroll
            for (int ni = 0; ni < 4; ++ni) {
                bf16x8 b = *(const bf16x8*)&Ks2[(ni * 16 + l16) * 128 + ks * 32 + quad * 8];
                sacc[ni] = __builtin_amdgcn_mfma_f32_16x16x32_bf16(a, b, sacc[ni], 0, 0, 0);
            }
        }
#pragma unroll
        for (int ni = 0; ni < 4; ++ni)
#pragma unroll
            for (int reg = 0; reg < 4; ++reg) {
                int r = wave * 16 + quad * 4 + reg, cc = ni * 16 + l16;
                float sv = sacc[ni][reg] * SCALE;
                if (kt * 64 + cc > qi * 64 + r) sv = -1e30f;
                Ss[r * 64 + cc] = sv;
            }
        __syncthreads();
        {
            int r = tid >> 2, j = tid & 3;
            float vals[16], mloc = -1e30f;
#pragma unroll
            for (int c = 0; c < 16; ++c) { vals[c] = Ss[r * 64 + j * 16 + c]; mloc = fmaxf(mloc, vals[c]); }
            mloc = fmaxf(mloc, __shfl_xor(mloc, 1));
            mloc = fmaxf(mloc, __shfl_xor(mloc, 2));
            float mold = mS[r], mnew = fmaxf(mold, mloc), ssum = 0.f;
#pragma unroll
            for (int c = 0; c < 16; ++c) {
                float p = __expf(vals[c] - mnew);
                ssum += p;
                Ps2[r * 64 + j * 16 + c] = (bf16)p;
            }
            ssum += __shfl_xor(ssum, 1);
            ssum += __shfl_xor(ssum, 2);
            if (j == 0) { float alpha = __expf(mold - mnew); mS[r] = mnew; lS[r] = lS[r] * alpha + ssum; aS[r] = alpha; }
        }
        __syncthreads();
        {
            float al2[4];
#pragma unroll
            for (int reg = 0; reg < 4; ++reg) al2[reg] = aS[wave * 16 + quad * 4 + reg];
#pragma unroll
            for (int ni = 0; ni < 8; ++ni)
#pragma unroll
                for (int reg = 0; reg < 4; ++reg) o_acc[ni][reg] *= al2[reg];
#pragma unroll
            for (int ks = 0; ks < 2; ++ks) {
                bf16x8 a = *(const bf16x8*)&Ps2[(wave * 16 + l16) * 64 + ks * 32 + quad * 8];
#pragma unroll
                for (int ni = 0; ni < 8; ++ni) {
                    bf16x8 b = *(const bf16x8*)&Vt2[(ni * 16 + l16) * 80 + ks * 32 + quad * 8];
                    o_acc[ni] = __builtin_amdgcn_mfma_f32_16x16x32_bf16(a, b, o_acc[ni], 0, 0, 0);
                }
            }
        }
        __syncthreads();
    }
    {
        float linv[4];
#pragma unroll
        for (int reg = 0; reg < 4; ++reg) linv[reg] = 1.f / fmaxf(lS[wave * 16 + quad * 4 + reg], 1e-20f);
#pragma unroll
        for (int ni = 0; ni < 8; ++ni)
#pragma unroll
            for (int reg = 0; reg < 4; ++reg) {
                int r = wave * 16 + quad * 4 + reg;
                obuf[(size_t)(qi * 64 + r) * HID + hh * HD + ni * 16 + l16] = (bf16)(o_acc[ni][reg] * linv[reg]);
            }
    }
}

// ---------------------------------------------------------------------------
extern "C" void kernel_launch(void* const* d_in, const int* in_sizes, int n_in,
                              void* d_out, int out_size, void* d_ws, size_t ws_size,
                              hipStream_t stream) {
    const float* x   = (const float*)d_in[0];
    const float* Wq  = (const float*)d_in[1];
    const float* bq  = (const float*)d_in[2];
    const float* Wk  = (const float*)d_in[3];
    const float* bk  = (const float*)d_in[4];
    const float* Wv  = (const float*)d_in[5];
    const float* bv  = (const float*)d_in[6];
    const float* Wo  = (const float*)d_in[7];
    const float* bo  = (const float*)d_in[8];
    const float* qg  = (const float*)d_in[9];
    const float* qbt = (const float*)d_in[10];
    const float* kg  = (const float*)d_in[11];
    const float* kbt = (const float*)d_in[12];
    float* out = (float*)d_out;

    // fast-path workspace layout (130,547,712 B):
    //   [0, 64MiB)           : xb (16MiB) | Wqkv (48MiB)   -- later aliased by OP (fp32 x2)
    //   [64MiB, 96MiB)       : Wob
    //   [96MiB, 120MiB)      : qkv (24MiB)                 -- later aliased by abuf (16MiB)
    //   [120MiB, 124MiB)     : vT
    //   [124MiB, +512KiB)    : lbuf
    const size_t NEED = 130547712;
    if (ws_size >= NEED) {
        char* p = (char*)d_ws;
        bf16*  xb   = (bf16*)p;
        bf16*  Wqkv = (bf16*)(p + 16777216);
        float* OP   = (float*)p;                       // aliases xb+Wqkv (both dead by attn)
        bf16*  Wob  = (bf16*)(p + 67108864);
        bf16*  qkv  = (bf16*)(p + 100663296);
        bf16*  abuf = (bf16*)(p + 100663296);          // aliases qkv (dead after attn)
        bf16*  vT   = (bf16*)(p + 125829120);
        float* lbuf = (float*)(p + 130023424);

        // fp32 -> bf16: x and packed W_qkv rows [Wq | Wk | Wv], plus Wo
        cvt<<<4096, 256, 0, stream>>>(x,  xb, 1048576);
        cvt<<<8192, 256, 0, stream>>>(Wq, Wqkv, 2097152);
        cvt<<<2048, 256, 0, stream>>>(Wk, Wqkv + (size_t)4096 * 4096, 524288);
        cvt<<<2048, 256, 0, stream>>>(Wv, Wqkv + (size_t)5120 * 4096, 524288);
        cvt<<<8192, 256, 0, stream>>>(Wo, Wob, 2097152);

        // fused QKV projection: [2048 x 6144], 256x192 tiles, 8-phase pipeline
        gemm8<256, 192, 2, 4, 1, bf16><<<dim3(32, 8), 512, 0, stream>>>(
            xb, Wqkv, bq, bk, bv, qkv, QSTR, 4096);

        // LN + RoPE in place (q pre-scaled by QSCL)
        ln_rope<<<dim3((S_LEN * (NH + NKV)) / 4), 256, 0, stream>>>(qkv, qg, qbt, kg, kbt);

        // v -> vT
        transpose_v<<<dim3(16, 32), 256, 0, stream>>>(qkv, vT);

        // balanced split-K attention -> fp32 partials, then merge
        attn3<<<dim3(64, 8), 256, 0, stream>>>(qkv, vT, OP, lbuf);
        merge<<<8192, 256, 0, stream>>>(OP, lbuf, abuf);

        // output projection: 256x128 tiles, 8-phase pipeline
        gemm8<256, 128, 4, 2, 0, float><<<dim3(32, 8), 512, 0, stream>>>(
            abuf, Wob, bo, bo, bo, out, 4096, 4096);
    } else {
        char* ws = (char*)d_ws;
        bf16* qbuf = (bf16*)(ws);
        bf16* kbuf = (bf16*)(ws + (16u << 20));
        bf16* vbuf = (bf16*)(ws + (20u << 20));
        bf16* abuf = (bf16*)(ws + (24u << 20));
        gemm_bt<float, bf16><<<dim3(32, 16), 256, 0, stream>>>(x, Wq, bq, qbuf, 4096, 4096);
        gemm_bt<float, bf16><<<dim3(8, 16), 256, 0, stream>>>(x, Wk, bk, kbuf, 1024, 4096);
        gemm_bt<float, bf16><<<dim3(8, 16), 256, 0, stream>>>(x, Wv, bv, vbuf, 1024, 4096);
        ln_rope_f<<<dim3((S_LEN * (NH + NKV)) / 4), 256, 0, stream>>>(qbuf, kbuf, qg, qbt, kg, kbt);
        attn_old<<<dim3(32, 32), 256, 0, stream>>>(qbuf, kbuf, vbuf, abuf);
        gemm_bt<bf16, float><<<dim3(32, 16), 256, 0, stream>>>(abuf, Wo, bo, out, 4096, 4096);
    }
}

// Round 3
// 556.758 us; speedup vs baseline: 1.2481x; 1.0389x over previous
//
#include <hip/hip_runtime.h>

typedef __bf16 bf16;
typedef __bf16 bf16x8 __attribute__((ext_vector_type(8)));
typedef __bf16 bf16x4 __attribute__((ext_vector_type(4)));
typedef float f32x4 __attribute__((ext_vector_type(4)));

#define S_LEN 2048
#define HID 4096
#define NH 32
#define NKV 8
#define HD 128
#define QSTR 6144                      // fused qkv row stride
#define SCALE 0.08838834764831845f
#define QSCL 0.1275164918918885f       // SCALE * log2(e)
#define M2C 16.33f                     // >= 128*QSCL = 16.3221 (Cauchy-Schwarz hard bound)

template <int V> struct IC { static constexpr int value = V; };

__device__ __forceinline__ bf16x8 load8(const bf16* p) { return *(const bf16x8*)p; }
__device__ __forceinline__ bf16x8 load8(const float* p) {
    float4 a = *(const float4*)p;
    float4 b = *(const float4*)(p + 4);
    bf16x8 r;
    r[0] = (bf16)a.x; r[1] = (bf16)a.y; r[2] = (bf16)a.z; r[3] = (bf16)a.w;
    r[4] = (bf16)b.x; r[5] = (bf16)b.y; r[6] = (bf16)b.z; r[7] = (bf16)b.w;
    return r;
}

__device__ __forceinline__ void load_lds16(const bf16* g, bf16* l) {
    __builtin_amdgcn_global_load_lds(
        (const __attribute__((address_space(1))) void*)g,
        (__attribute__((address_space(3))) void*)l, 16, 0, 0);
}

template <int C> __device__ __forceinline__ void vmwait_if() {
    if constexpr (C >= 0) asm volatile("s_waitcnt vmcnt(%0)" ::"n"(C) : "memory");
}

__device__ __forceinline__ void lgkm0() {
    asm volatile("s_waitcnt lgkmcnt(0)" ::: "memory");
    __builtin_amdgcn_sched_barrier(0);
}

// ---------------------------------------------------------------------------
// fused fp32 -> bf16 bulk convert: x | Wq | Wk | Wv -> xb,Wqkv ; Wo -> Wob
// region bounds in 8-float granules.
// ---------------------------------------------------------------------------
__global__ __launch_bounds__(256) void cvt5(const float* __restrict__ x,
                                            const float* __restrict__ Wq,
                                            const float* __restrict__ Wk,
                                            const float* __restrict__ Wv,
                                            const float* __restrict__ Wo,
                                            bf16* __restrict__ xb,
                                            bf16* __restrict__ Wqkv,
                                            bf16* __restrict__ Wob) {
    int i = blockIdx.x * 256 + threadIdx.x;
    const float* src;
    bf16* dst;
    if (i < 1048576)      { src = x  + (size_t)i * 8;              dst = xb + (size_t)i * 8; }
    else if (i < 3145728) { size_t j = i - 1048576; src = Wq + j * 8; dst = Wqkv + j * 8; }
    else if (i < 3670016) { size_t j = i - 3145728; src = Wk + j * 8; dst = Wqkv + 16777216 + j * 8; }
    else if (i < 4194304) { size_t j = i - 3670016; src = Wv + j * 8; dst = Wqkv + 20971520 + j * 8; }
    else                  { size_t j = i - 4194304; src = Wo + j * 8; dst = Wob + j * 8; }
    *(bf16x8*)dst = load8(src);
}

// ---------------------------------------------------------------------------
// 8-phase pipelined GEMM (m201-style): out[M,N] = A[M,K] @ B[N,K]^T + bias.
// BK=64, double-buffered LDS; counted vmcnt (never 0 in steady state),
// setprio around MFMA clusters, granule-XOR swizzle (0 bank conflicts).
// ---------------------------------------------------------------------------
template <int BM, int BN, int WM, int WN, int BMODE, typename TO>
__global__ __launch_bounds__(512, 2) void gemm8(const bf16* __restrict__ A,
                                                const bf16* __restrict__ Bw,
                                                const float* __restrict__ b0,
                                                const float* __restrict__ b1,
                                                const float* __restrict__ b2,
                                                TO* __restrict__ out,
                                                int N, int K) {
    constexpr int RW  = BM / WM;
    constexpr int CW  = BN / WN;
    constexpr int FM  = RW / 16;
    constexpr int FN  = CW / 16;
    constexpr int FMH = FM / 2;
    constexpr int FNH0 = (FN + 1) / 2, FNH1 = FN - FNH0;
    constexpr int SZ0 = FNH0 * 16, SZ1 = FNH1 * 16;
    constexpr int AROWS_H = BM / 2;
    constexpr int B0ROWS = WN * SZ0, B1ROWS = WN * SZ1;
    constexpr int LA  = AROWS_H / 64;
    constexpr int LB0 = B0ROWS / 64, LB1 = B1ROWS / 64;
    constexpr int V0  = 2 * LA + LB0;
    constexpr int V3  = 2 * LA + LB0 + LB1;
    constexpr int V3T = LA + LB1;

    __shared__ __align__(16) bf16 AS[2 * BM * 64];
    __shared__ __align__(16) bf16 BS[2 * BN * 64];

    const int tid  = threadIdx.x;
    const int wave = tid >> 6;
    const int lane = tid & 63;
    const int quad = lane >> 4;
    const int l16  = lane & 15;
    const int wm   = wave / WN;
    const int wn   = wave % WN;

    const int gx   = gridDim.x;
    const int nwg  = gx * gridDim.y;
    const int orig = blockIdx.y * gx + blockIdx.x;
    int wg = orig;
    if ((nwg & 7) == 0) wg = (orig & 7) * (nwg >> 3) + (orig >> 3);
    const int row0 = (wg / gx) * BM;
    const int col0 = (wg % gx) * BN;

    auto stageA = [&](int mh, int bufv, int kt) {
#pragma unroll
        for (int j = 0; j < LA; ++j) {
            int c = j * 512 + tid;
            int r = c >> 3, pg = c & 7;
            int g = pg ^ (r & 7);
            int gr = (r / (RW / 2)) * RW + mh * (RW / 2) + (r % (RW / 2));
            load_lds16(&A[(size_t)(row0 + gr) * K + kt * 64 + g * 8],
                       &AS[bufv * (BM * 64) + mh * (AROWS_H * 64) + c * 8]);
        }
    };
    auto stageB0 = [&](int bufv, int kt) {
#pragma unroll
        for (int j = 0; j < LB0; ++j) {
            int c = j * 512 + tid;
            int r = c >> 3, pg = c & 7;
            int g = pg ^ (r & 7);
            int gc = (r / SZ0) * CW + (r % SZ0);
            load_lds16(&Bw[(size_t)(col0 + gc) * K + kt * 64 + g * 8],
                       &BS[bufv * (BN * 64) + c * 8]);
        }
    };
    auto stageB1 = [&](int bufv, int kt) {
#pragma unroll
        for (int j = 0; j < LB1; ++j) {
            int c = j * 512 + tid;
            int r = c >> 3, pg = c & 7;
            int g = pg ^ (r & 7);
            int gc = (r / SZ1) * CW + SZ0 + (r % SZ1);
            load_lds16(&Bw[(size_t)(col0 + gc) * K + kt * 64 + g * 8],
                       &BS[bufv * (BN * 64) + B0ROWS * 64 + c * 8]);
        }
    };

    f32x4 acc[FM][FN];
#pragma unroll
    for (int mi = 0; mi < FM; ++mi)
#pragma unroll
        for (int ni = 0; ni < FN; ++ni) { f32x4 z = {0.f, 0.f, 0.f, 0.f}; acc[mi][ni] = z; }

    bf16x8 af[FMH][2];
    bf16x8 bfv[FN][2];

    auto loadA = [&](int mh, int bufv) {
#pragma unroll
        for (int mi = 0; mi < FMH; ++mi)
#pragma unroll
            for (int ks = 0; ks < 2; ++ks) {
                int r = wm * (RW / 2) + mi * 16 + l16;
                int g = ks * 4 + quad;
                af[mi][ks] = *(const bf16x8*)&AS[bufv * (BM * 64) + mh * (AROWS_H * 64) +
                                                 r * 64 + ((g ^ (r & 7)) << 3)];
            }
    };
    auto loadB = [&](auto cNH, int bufv) {
        constexpr int NHv = decltype(cNH)::value;
        constexpr int CNT = NHv ? FNH1 : FNH0;
        constexpr int SZ  = NHv ? SZ1 : SZ0;
#pragma unroll
        for (int nj = 0; nj < CNT; ++nj)
#pragma unroll
            for (int ks = 0; ks < 2; ++ks) {
                int r = wn * SZ + nj * 16 + l16;
                int g = ks * 4 + quad;
                bfv[NHv * FNH0 + nj][ks] =
                    *(const bf16x8*)&BS[bufv * (BN * 64) + NHv * (B0ROWS * 64) +
                                        r * 64 + ((g ^ (r & 7)) << 3)];
            }
    };
    auto mmac = [&](auto cMH, auto cNH) {
        constexpr int MH = decltype(cMH)::value, NHv = decltype(cNH)::value;
        constexpr int NB = NHv ? FNH0 : 0, NE = NHv ? FN : FNH0;
        __builtin_amdgcn_s_setprio(1);
#pragma unroll
        for (int mi = 0; mi < FMH; ++mi)
#pragma unroll
            for (int ni = NB; ni < NE; ++ni)
#pragma unroll
                for (int ks = 0; ks < 2; ++ks)
                    acc[MH * FMH + mi][ni] = __builtin_amdgcn_mfma_f32_16x16x32_bf16(
                        af[mi][ks], bfv[ni][ks], acc[MH * FMH + mi][ni], 0, 0, 0);
        __builtin_amdgcn_s_setprio(0);
    };

    auto run_tile = [&](int t, auto cSA1, auto cSB1, auto cSA0, auto cSB0,
                        auto cV0, auto cV3) {
        const int buf = t & 1, nbuf = buf ^ 1;
        loadA(0, buf);
        loadB(IC<0>{}, buf);
        if constexpr (decltype(cSA1)::value) stageA(1, nbuf, t + 1);
        __builtin_amdgcn_s_barrier();
        lgkm0();
        mmac(IC<0>{}, IC<0>{});
        vmwait_if<decltype(cV0)::value>();
        __builtin_amdgcn_s_barrier();
        loadB(IC<1>{}, buf);
        if constexpr (decltype(cSB1)::value) stageB1(nbuf, t + 1);
        __builtin_amdgcn_s_barrier();
        lgkm0();
        mmac(IC<0>{}, IC<1>{});
        __builtin_amdgcn_s_barrier();
        loadA(1, buf);
        if constexpr (decltype(cSA0)::value) stageA(0, buf, t + 2);
        __builtin_amdgcn_s_barrier();
        lgkm0();
        mmac(IC<1>{}, IC<0>{});
        __builtin_amdgcn_s_barrier();
        if constexpr (decltype(cSB0)::value) stageB0(buf, t + 2);
        __builtin_amdgcn_s_barrier();
        lgkm0();
        mmac(IC<1>{}, IC<1>{});
        vmwait_if<decltype(cV3)::value>();
        __builtin_amdgcn_s_barrier();
    };

    stageA(0, 0, 0); stageB0(0, 0);
    stageA(1, 0, 0); stageB1(0, 0);
    stageA(0, 1, 1); stageB0(1, 1);
    vmwait_if<V3>();
    __builtin_amdgcn_s_barrier();

    const int NT = K >> 6;
    for (int t = 0; t < NT - 2; ++t)
        run_tile(t, IC<1>{}, IC<1>{}, IC<1>{}, IC<1>{}, IC<V0>{}, IC<V3>{});
    run_tile(NT - 2, IC<1>{}, IC<1>{}, IC<0>{}, IC<0>{}, IC<V0>{}, IC<V3T>{});
    run_tile(NT - 1, IC<0>{}, IC<0>{}, IC<0>{}, IC<0>{}, IC<0>{}, IC<-1>{});

#pragma unroll
    for (int ni = 0; ni < FN; ++ni) {
        int n = col0 + wn * CW + ni * 16 + l16;
        float bv;
        if (BMODE == 0) bv = b0[n];
        else bv = (n < 4096) ? b0[n] : ((n < 5120) ? b1[n - 4096] : b2[n - 5120]);
#pragma unroll
        for (int mi = 0; mi < FM; ++mi) {
            int m = row0 + wm * RW + mi * 16 + quad * 4;
#pragma unroll
            for (int reg = 0; reg < 4; ++reg)
                out[(size_t)(m + reg) * N + n] = (TO)(acc[mi][ni][reg] + bv);
        }
    }
}

// ---------------------------------------------------------------------------
// LayerNorm(HD=128) + RoPE in place on fused qkv buffer (stride QSTR).
// q rows additionally pre-scaled by QSCL (softmax works in log2 domain).
// ---------------------------------------------------------------------------
__global__ __launch_bounds__(256) void ln_rope(bf16* __restrict__ qkv,
                                               const float* __restrict__ qg, const float* __restrict__ qbt,
                                               const float* __restrict__ kg, const float* __restrict__ kbt) {
    int row  = blockIdx.x * 4 + (threadIdx.x >> 6);
    int lane = threadIdx.x & 63;

    bf16* ptr;
    const float *g, *bb;
    int s;
    float osc;
    if (row < S_LEN * NH) {
        s   = row >> 5;
        ptr = qkv + (size_t)s * QSTR + (row & 31) * HD;
        g   = qg; bb = qbt; osc = QSCL;
    } else {
        int r2 = row - S_LEN * NH;
        s   = r2 >> 3;
        ptr = qkv + (size_t)s * QSTR + 4096 + (r2 & 7) * HD;
        g   = kg; bb = kbt; osc = 1.f;
    }

    float x1 = (float)ptr[lane];
    float x2 = (float)ptr[lane + 64];
    float sum = x1 + x2;
    float sq  = x1 * x1 + x2 * x2;
#pragma unroll
    for (int m = 1; m < 64; m <<= 1) {
        sum += __shfl_xor(sum, m);
        sq  += __shfl_xor(sq, m);
    }
    float mu  = sum * (1.f / 128.f);
    float var = sq * (1.f / 128.f) - mu * mu;
    float rs  = rsqrtf(var + 1e-5f);
    float n1  = (x1 - mu) * rs * g[lane] + bb[lane];
    float n2  = (x2 - mu) * rs * g[lane + 64] + bb[lane + 64];

    // 500000^(-lane/64) = exp2(-lane * log2(5e5)/64)
    float inv = exp2f(-0.2958057514f * (float)lane);
    float ang = (float)s * inv;
    float sn, cs;
    sincosf(ang, &sn, &cs);

    ptr[lane]      = (bf16)((n1 * cs - n2 * sn) * osc);
    ptr[lane + 64] = (bf16)((n2 * cs + n1 * sn) * osc);
}

// ---------------------------------------------------------------------------
// Transpose v (cols 5120..6143 of qkv, [s][c]) -> vT [c][s]. 64x64 LDS tiles,
// XOR-swizzled (write b128 free; read 8xb16 2-way = free).
// ---------------------------------------------------------------------------
__global__ __launch_bounds__(256) void transpose_v(const bf16* __restrict__ qkv,
                                                   bf16* __restrict__ vT) {
    __shared__ bf16 Ts[64 * 64];
    const int c0 = blockIdx.x * 64;
    const int s0 = blockIdx.y * 64;
    const int tid = threadIdx.x;

#pragma unroll
    for (int i = 0; i < 2; ++i) {
        int cc = i * 256 + tid;
        int r = cc >> 3, col8 = cc & 7;
        *(bf16x8*)&Ts[r * 64 + ((col8 ^ (r & 7)) << 3)] =
            *(const bf16x8*)&qkv[(size_t)(s0 + r) * QSTR + 5120 + c0 + (col8 << 3)];
    }
    __syncthreads();
#pragma unroll
    for (int i = 0; i < 2; ++i) {
        int oc = i * 256 + tid;
        int c = oc & 63, sb = oc >> 6;
        bf16x8 r8;
#pragma unroll
        for (int j = 0; j < 8; ++j) {
            int sg = sb * 8 + j;
            r8[j] = Ts[sg * 64 + ((((c >> 3) ^ (sg & 7)) << 3) + (c & 7))];
        }
        *(bf16x8*)&vT[(size_t)(c0 + c) * S_LEN + s0 + sb * 8] = r8;
    }
}

// ---------------------------------------------------------------------------
// Flash attention v4: fused split-K with in-LDS merge (no HBM partials).
// Block = (pair p, kvh), 512 threads = 8 waves = 4 heads x 2 kt-parities.
// Processes Q-tiles p and 63-p (32 rows each); per iteration stages TWO K/V
// tiles (kt=2it, 2it+1); wave parity spw consumes its own tile. Fixed-max
// log2-domain softmax; row sums via MFMA ones-trick. Epilogue: spw=1 waves
// dump o_acc/lacc to the (now free) K/V LDS, spw=0 adds, normalizes, writes
// bf16 output directly. Work per block = 17 iterations for every p.
// ---------------------------------------------------------------------------
__global__ __launch_bounds__(512) void attn4(const bf16* __restrict__ qkv,
                                             const bf16* __restrict__ vT,
                                             bf16* __restrict__ abuf) {
    const int pairp = blockIdx.x;
    const int kvh   = blockIdx.y;
    const int tid   = threadIdx.x;
    const int wave  = tid >> 6;
    const int lane  = tid & 63;
    const int quad  = lane >> 4;
    const int l16   = lane & 15;
    const int spw   = wave >> 2;       // kt parity this wave handles
    const int hw    = wave & 3;        // head within kv group
    const int h     = kvh * 4 + hw;

    // single LDS pool: K[2][64*128] | V[2][128*64] | Ps[8][32*64]  (96 KiB)
    __shared__ __align__(16) bf16 smem[2 * 64 * 128 + 2 * 128 * 64 + 8 * 32 * 64];
    __shared__ float Ls[8][32];
    bf16* Ksb = smem;                                  // per-tile stride 8192
    bf16* Vtb = smem + 2 * 64 * 128;
    bf16* Psb = smem + 2 * 64 * 128 + 2 * 128 * 64;    // per-wave stride 2048

    bf16x8 onesf;
#pragma unroll
    for (int j = 0; j < 8; ++j) onesf[j] = (bf16)1.f;

    int4 pk[4], pv[4];

    for (int ph = 0; ph < 2; ++ph) {
        const int qt  = ph ? (63 - pairp) : pairp;
        const int r0  = qt * 32;
        const int nkt = qt / 2 + 1;
        const int nit = (nkt + 1) >> 1;    // K/V tile PAIRS

        // Q fragments (already scaled by QSCL in ln_rope)
        bf16x8 qf[2][4];
#pragma unroll
        for (int mi = 0; mi < 2; ++mi)
#pragma unroll
            for (int ks = 0; ks < 4; ++ks)
                qf[mi][ks] = *(const bf16x8*)&qkv[(size_t)(r0 + mi * 16 + l16) * QSTR +
                                                  h * HD + ks * 32 + quad * 8];

        f32x4 o_acc[2][8];
#pragma unroll
        for (int mi = 0; mi < 2; ++mi)
#pragma unroll
            for (int ni = 0; ni < 8; ++ni) {
                f32x4 z = {0.f, 0.f, 0.f, 0.f};
                o_acc[mi][ni] = z;
            }
        f32x4 lacc[2];
#pragma unroll
        for (int mi = 0; mi < 2; ++mi) { f32x4 z = {0.f, 0.f, 0.f, 0.f}; lacc[mi] = z; }

        auto load_regs = [&](int kt0) {   // prefetch tiles kt0, kt0+1 into regs
#pragma unroll
            for (int i = 0; i < 4; ++i) {
                int cc = i * 512 + tid;
                int tile = cc >> 10, g = cc & 1023;
                int key = g >> 4, d8 = g & 15;
                pk[i] = *(const int4*)&qkv[(size_t)((kt0 + tile) * 64 + key) * QSTR + 4096 +
                                           kvh * HD + (d8 << 3)];
            }
#pragma unroll
            for (int i = 0; i < 4; ++i) {
                int cc = i * 512 + tid;
                int tile = cc >> 10, g = cc & 1023;
                int d = g >> 3, k8 = g & 7;
                pv[i] = *(const int4*)&vT[(size_t)(kvh * HD + d) * S_LEN +
                                          (kt0 + tile) * 64 + (k8 << 3)];
            }
        };

        load_regs(0);

        for (int it = 0; it < nit; ++it) {
            // drain prefetch regs into swizzled LDS (both tiles)
#pragma unroll
            for (int i = 0; i < 4; ++i) {
                int cc = i * 512 + tid;
                int tile = cc >> 10, g = cc & 1023;
                int key = g >> 4, d8 = g & 15;
                *(int4*)&Ksb[tile * 8192 + key * 128 + ((d8 ^ (key & 7)) << 3)] = pk[i];
            }
#pragma unroll
            for (int i = 0; i < 4; ++i) {
                int cc = i * 512 + tid;
                int tile = cc >> 10, g = cc & 1023;
                int d = g >> 3, k8 = g & 7;
                *(int4*)&Vtb[tile * 8192 + d * 64 + ((k8 ^ (d & 7)) << 3)] = pv[i];
            }
            __syncthreads();

            if (it + 1 < nit) load_regs(2 * (it + 1));

            const int kt = 2 * it + spw;
            if (kt < nkt) {
                const bf16* Kw = Ksb + spw * 8192;
                const bf16* Vw = Vtb + spw * 8192;
                bf16* Pw = Psb + wave * 2048;

                // S = Q K^T (log2-scaled)
                f32x4 sacc[2][4];
#pragma unroll
                for (int mi = 0; mi < 2; ++mi)
#pragma unroll
                    for (int ni = 0; ni < 4; ++ni) {
                        f32x4 z = {0.f, 0.f, 0.f, 0.f};
                        sacc[mi][ni] = z;
                    }
#pragma unroll
                for (int ks = 0; ks < 4; ++ks)
#pragma unroll
                    for (int ni = 0; ni < 4; ++ni) {
                        bf16x8 kf = *(const bf16x8*)&Kw[(ni * 16 + l16) * 128 +
                                                        ((((ks << 2) + quad) ^ (l16 & 7)) << 3)];
                        sacc[0][ni] = __builtin_amdgcn_mfma_f32_16x16x32_bf16(qf[0][ks], kf, sacc[0][ni], 0, 0, 0);
                        sacc[1][ni] = __builtin_amdgcn_mfma_f32_16x16x32_bf16(qf[1][ks], kf, sacc[1][ni], 0, 0, 0);
                    }

                // fixed-max softmax: p = exp2(s2 - M2C); masked -> 0
#pragma unroll
                for (int mi = 0; mi < 2; ++mi)
#pragma unroll
                    for (int reg = 0; reg < 4; ++reg) {
                        int rloc = mi * 16 + quad * 4 + reg;
                        int qrow = r0 + rloc;
#pragma unroll
                        for (int ni = 0; ni < 4; ++ni) {
                            int key = kt * 64 + ni * 16 + l16;
                            float t = (key > qrow) ? -1e30f : (sacc[mi][ni][reg] - M2C);
                            float p = exp2f(t);
                            int blk = (ni * 2 + (l16 >> 3)) ^ (rloc & 7);
                            Pw[rloc * 64 + blk * 8 + (l16 & 7)] = (bf16)p;
                        }
                    }

                // O += P @ V ; l += P @ ones  (per-wave Ps: no barrier needed)
#pragma unroll
                for (int ks2 = 0; ks2 < 2; ++ks2) {
                    bf16x8 pa[2];
#pragma unroll
                    for (int mi = 0; mi < 2; ++mi) {
                        int rloc = mi * 16 + l16;
                        pa[mi] = *(const bf16x8*)&Pw[rloc * 64 +
                                                     ((((ks2 << 2) + quad) ^ (rloc & 7)) << 3)];
                    }
#pragma unroll
                    for (int ni = 0; ni < 8; ++ni) {
                        int d = ni * 16 + l16;
                        bf16x8 vf = *(const bf16x8*)&Vw[d * 64 + ((((ks2 << 2) + quad) ^ (d & 7)) << 3)];
                        o_acc[0][ni] = __builtin_amdgcn_mfma_f32_16x16x32_bf16(pa[0], vf, o_acc[0][ni], 0, 0, 0);
                        o_acc[1][ni] = __builtin_amdgcn_mfma_f32_16x16x32_bf16(pa[1], vf, o_acc[1][ni], 0, 0, 0);
                    }
                    lacc[0] = __builtin_amdgcn_mfma_f32_16x16x32_bf16(pa[0], onesf, lacc[0], 0, 0, 0);
                    lacc[1] = __builtin_amdgcn_mfma_f32_16x16x32_bf16(pa[1], onesf, lacc[1], 0, 0, 0);
                }
            }
            __syncthreads();
        }

        // cross-parity merge via LDS (K/V region free: 64 KiB fp32 scratch)
        float* M = (float*)smem;
        if (spw == 1) {
            float* Mw = M + hw * 4096;
#pragma unroll
            for (int mi = 0; mi < 2; ++mi)
#pragma unroll
                for (int ni = 0; ni < 8; ++ni)
#pragma unroll
                    for (int j = 0; j < 4; ++j)
                        Mw[((mi * 8 + ni) * 4 + j) * 64 + lane] = o_acc[mi][ni][j];
            if (l16 == 0)
#pragma unroll
                for (int mi = 0; mi < 2; ++mi)
#pragma unroll
                    for (int reg = 0; reg < 4; ++reg)
                        Ls[wave][mi * 16 + quad * 4 + reg] = lacc[mi][reg];
        }
        __syncthreads();
        if (spw == 0) {
            float* Mw = M + hw * 4096;
#pragma unroll
            for (int mi = 0; mi < 2; ++mi) {
                float linv[4];
#pragma unroll
                for (int reg = 0; reg < 4; ++reg)
                    linv[reg] = 1.f / fmaxf(lacc[mi][reg] +
                                            Ls[wave + 4][mi * 16 + quad * 4 + reg], 1e-30f);
#pragma unroll
                for (int ni = 0; ni < 8; ++ni)
#pragma unroll
                    for (int reg = 0; reg < 4; ++reg) {
                        float v = o_acc[mi][ni][reg] + Mw[((mi * 8 + ni) * 4 + reg) * 64 + lane];
                        int s = r0 + mi * 16 + quad * 4 + reg;
                        abuf[(size_t)s * HID + h * HD + ni * 16 + l16] = (bf16)(v * linv[reg]);
                    }
            }
        }
        __syncthreads();
    }
}

// ===========================================================================
// Fallback path (round-3, proven) — only if workspace is unexpectedly small.
// ===========================================================================
template <typename TA, typename TO>
__global__ __launch_bounds__(256) void gemm_bt(const TA* __restrict__ A,
                                               const float* __restrict__ W,
                                               const float* __restrict__ bias,
                                               TO* __restrict__ out,
                                               int N, int K) {
    __shared__ __align__(16) bf16 As[128 * 64];
    __shared__ __align__(16) bf16 Bs[128 * 64];
    const int tid = threadIdx.x, wave = tid >> 6, lane = tid & 63;
    const int quad = lane >> 4, l16 = lane & 15, wm = wave >> 1, wn = wave & 1;
    const int row0 = blockIdx.y * 128, col0 = blockIdx.x * 128;
    f32x4 acc[4][4];
#pragma unroll
    for (int mi = 0; mi < 4; ++mi)
#pragma unroll
        for (int ni = 0; ni < 4; ++ni) { f32x4 z = {0.f,0.f,0.f,0.f}; acc[mi][ni] = z; }
    for (int k0 = 0; k0 < K; k0 += 64) {
#pragma unroll
        for (int i = 0; i < 4; ++i) {
            int c = i * 256 + tid, r = c >> 3, col8 = (c & 7) << 3;
            *(bf16x8*)&As[r * 64 + col8] = load8(&A[(size_t)(row0 + r) * K + k0 + col8]);
            *(bf16x8*)&Bs[r * 64 + col8] = load8(&W[(size_t)(col0 + r) * K + k0 + col8]);
        }
        __syncthreads();
#pragma unroll
        for (int ks = 0; ks < 2; ++ks) {
            bf16x8 af[4], bfr[4];
#pragma unroll
            for (int mi = 0; mi < 4; ++mi)
                af[mi] = *(const bf16x8*)&As[(wm * 64 + mi * 16 + l16) * 64 + ks * 32 + quad * 8];
#pragma unroll
            for (int ni = 0; ni < 4; ++ni)
                bfr[ni] = *(const bf16x8*)&Bs[(wn * 64 + ni * 16 + l16) * 64 + ks * 32 + quad * 8];
#pragma unroll
            for (int mi = 0; mi < 4; ++mi)
#pragma unroll
                for (int ni = 0; ni < 4; ++ni)
                    acc[mi][ni] = __builtin_amdgcn_mfma_f32_16x16x32_bf16(af[mi], bfr[ni], acc[mi][ni], 0, 0, 0);
        }
        __syncthreads();
    }
#pragma unroll
    for (int ni = 0; ni < 4; ++ni) {
        int n = col0 + wn * 64 + ni * 16 + l16;
        float bv = bias[n];
#pragma unroll
        for (int mi = 0; mi < 4; ++mi) {
            int m = row0 + wm * 64 + mi * 16 + quad * 4;
#pragma unroll
            for (int reg = 0; reg < 4; ++reg)
                out[(size_t)(m + reg) * N + n] = (TO)(acc[mi][ni][reg] + bv);
        }
    }
}

__global__ __launch_bounds__(256) void ln_rope_f(bf16* __restrict__ qb, bf16* __restrict__ kb,
                                                 const float* __restrict__ qg, const float* __restrict__ qbt,
                                                 const float* __restrict__ kg, const float* __restrict__ kbt) {
    int row = blockIdx.x * 4 + (threadIdx.x >> 6);
    int lane = threadIdx.x & 63;
    bf16* ptr; const float *g, *bb; int s;
    if (row < S_LEN * NH) { s = row >> 5; ptr = qb + (size_t)s * (NH * HD) + (row & 31) * HD; g = qg; bb = qbt; }
    else { int r2 = row - S_LEN * NH; s = r2 >> 3; ptr = kb + (size_t)s * (NKV * HD) + (r2 & 7) * HD; g = kg; bb = kbt; }
    float x1 = (float)ptr[lane], x2 = (float)ptr[lane + 64];
    float sum = x1 + x2, sq = x1 * x1 + x2 * x2;
#pragma unroll
    for (int m = 1; m < 64; m <<= 1) { sum += __shfl_xor(sum, m); sq += __shfl_xor(sq, m); }
    float mu = sum * (1.f / 128.f), var = sq * (1.f / 128.f) - mu * mu;
    float rs = rsqrtf(var + 1e-5f);
    float n1 = (x1 - mu) * rs * g[lane] + bb[lane];
    float n2 = (x2 - mu) * rs * g[lane + 64] + bb[lane + 64];
    float inv = powf(500000.f, -(float)lane * (1.f / 64.f));
    float ang = (float)s * inv, sn, cs;
    sincosf(ang, &sn, &cs);
    ptr[lane] = (bf16)(n1 * cs - n2 * sn);
    ptr[lane + 64] = (bf16)(n2 * cs + n1 * sn);
}

__global__ __launch_bounds__(256) void attn_old(const bf16* __restrict__ qbuf,
                                                const bf16* __restrict__ kbuf,
                                                const bf16* __restrict__ vbuf,
                                                bf16* __restrict__ obuf) {
    const int qi = blockIdx.x, hh = blockIdx.y, kvh = hh >> 2;
    __shared__ __align__(16) bf16 Qs[64 * 128];
    __shared__ __align__(16) bf16 Ks2[64 * 128];
    __shared__ __align__(16) bf16 Vt2[128 * 80];
    __shared__ __align__(16) float Ss[64 * 64];
    __shared__ __align__(16) bf16 Ps2[64 * 64];
    __shared__ float mS[64], lS[64], aS[64];
    const int tid = threadIdx.x, wave = tid >> 6, lane = tid & 63;
    const int quad = lane >> 4, l16 = lane & 15;
#pragma unroll
    for (int i = 0; i < 4; ++i) {
        int c = i * 256 + tid, r = c >> 4, col8 = (c & 15) << 3;
        *(int4*)&Qs[r * 128 + col8] = *(const int4*)&qbuf[(size_t)(qi * 64 + r) * HID + hh * HD + col8];
    }
    if (tid < 64) { mS[tid] = -1e30f; lS[tid] = 0.f; }
    f32x4 o_acc[8];
#pragma unroll
    for (int i = 0; i < 8; ++i) { f32x4 z = {0.f,0.f,0.f,0.f}; o_acc[i] = z; }
    __syncthreads();
    for (int kt = 0; kt <= qi; ++kt) {
#pragma unroll
        for (int i = 0; i < 4; ++i) {
            int c = i * 256 + tid, r = c >> 4, col8 = (c & 15) << 3;
            const size_t gofs = (size_t)(kt * 64 + r) * (NKV * HD) + kvh * HD + col8;
            *(int4*)&Ks2[r * 128 + col8] = *(const int4*)&kbuf[gofs];
            bf16x8 vv = *(const bf16x8*)&vbuf[gofs];
#pragma unroll
            for (int e = 0; e < 8; ++e) Vt2[(col8 + e) * 80 + r] = vv[e];
        }
        __syncthreads();
        f32x4 sacc[4];
#pragma unroll
        for (int ni = 0; ni < 4; ++ni) { f32x4 z = {0.f,0.f,0.f,0.f}; sacc[ni] = z; }
#pragma unroll
        for (int ks = 0; ks < 4; ++ks) {
            bf16x8 a = *(const bf16x8*)&Qs[(wave * 16 + l16) * 128 + ks * 32 + quad * 8];
#pragma unroll
            for (int ni = 0; ni < 4; ++ni) {
                bf16x8 b = *(const bf16x8*)&Ks2[(ni * 16 + l16) * 128 + ks * 32 + quad * 8];
                sacc[ni] = __builtin_amdgcn_mfma_f32_16x16x32_bf16(a, b, sacc[ni], 0, 0, 0);
            }
        }
#pragma unroll
        for (int ni = 0; ni < 4; ++ni)
#pragma unroll
            for (int reg = 0; reg < 4; ++reg) {
                int r = wave * 16 + quad * 4 + reg, cc = ni * 16 + l16;
                float sv = sacc[ni][reg] * SCALE;
                if (kt * 64 + cc > qi * 64 + r) sv = -1e30f;
                Ss[r * 64 + cc] = sv;
            }
        __syncthreads();
        {
            int r = tid >> 2, j = tid & 3;
            float vals[16], mloc = -1e30f;
#pragma unroll
            for (int c = 0; c < 16; ++c) { vals[c] = Ss[r * 64 + j * 16 + c]; mloc = fmaxf(mloc, vals[c]); }
            mloc = fmaxf(mloc, __shfl_xor(mloc, 1));
            mloc = fmaxf(mloc, __shfl_xor(mloc, 2));
            float mold = mS[r], mnew = fmaxf(mold, mloc), ssum = 0.f;
#pragma unroll
            for (int c = 0; c < 16; ++c) {
                float p = __expf(vals[c] - mnew);
                ssum += p;
                Ps2[r * 64 + j * 16 + c] = (bf16)p;
            }
            ssum += __shfl_xor(ssum, 1);
            ssum += __shfl_xor(ssum, 2);
            if (j == 0) { float alpha = __expf(mold - mnew); mS[r] = mnew; lS[r] = lS[r] * alpha + ssum; aS[r] = alpha; }
        }
        __syncthreads();
        {
            float al2[4];
#pragma unroll
            for (int reg = 0; reg < 4; ++reg) al2[reg] = aS[wave * 16 + quad * 4 + reg];
#pragma unroll
            for (int ni = 0; ni < 8; ++ni)
#pragma unroll
                for (int reg = 0; reg < 4; ++reg) o_acc[ni][reg] *= al2[reg];
#pragma unroll
            for (int ks = 0; ks < 2; ++ks) {
                bf16x8 a = *(const bf16x8*)&Ps2[(wave * 16 + l16) * 64 + ks * 32 + quad * 8];
#pragma unroll
                for (int ni = 0; ni < 8; ++ni) {
                    bf16x8 b = *(const bf16x8*)&Vt2[(ni * 16 + l16) * 80 + ks * 32 + quad * 8];
                    o_acc[ni] = __builtin_amdgcn_mfma_f32_16x16x32_bf16(a, b, o_acc[ni], 0, 0, 0);
                }
            }
        }
        __syncthreads();
    }
    {
        float linv[4];
#pragma unroll
        for (int reg = 0; reg < 4; ++reg) linv[reg] = 1.f / fmaxf(lS[wave * 16 + quad * 4 + reg], 1e-20f);
#pragma unroll
        for (int ni = 0; ni < 8; ++ni)
#pragma unroll
            for (int reg = 0; reg < 4; ++reg) {
                int r = wave * 16 + quad * 4 + reg;
                obuf[(size_t)(qi * 64 + r) * HID + hh * HD + ni * 16 + l16] = (bf16)(o_acc[ni][reg] * linv[reg]);
            }
    }
}

// ---------------------------------------------------------------------------
extern "C" void kernel_launch(void* const* d_in, const int* in_sizes, int n_in,
                              void* d_out, int out_size, void* d_ws, size_t ws_size,
                              hipStream_t stream) {
    const float* x   = (const float*)d_in[0];
    const float* Wq  = (const float*)d_in[1];
    const float* bq  = (const float*)d_in[2];
    const float* Wk  = (const float*)d_in[3];
    const float* bk  = (const float*)d_in[4];
    const float* Wv  = (const float*)d_in[5];
    const float* bv  = (const float*)d_in[6];
    const float* Wo  = (const float*)d_in[7];
    const float* bo  = (const float*)d_in[8];
    const float* qg  = (const float*)d_in[9];
    const float* qbt = (const float*)d_in[10];
    const float* kg  = (const float*)d_in[11];
    const float* kbt = (const float*)d_in[12];
    float* out = (float*)d_out;

    // fast-path workspace layout (130,547,712 B):
    //   [0, 16MiB)           : xb  -- later aliased by abuf (attn4 bf16 out)
    //   [16MiB, 64MiB)       : Wqkv
    //   [64MiB, 96MiB)       : Wob
    //   [96MiB, 120MiB)      : qkv
    //   [120MiB, 124MiB)     : vT
    const size_t NEED = 130547712;
    if (ws_size >= NEED) {
        char* p = (char*)d_ws;
        bf16*  xb   = (bf16*)p;
        bf16*  Wqkv = (bf16*)(p + 16777216);
        bf16*  abuf = (bf16*)p;                        // aliases xb (dead after QKV gemm)
        bf16*  Wob  = (bf16*)(p + 67108864);
        bf16*  qkv  = (bf16*)(p + 100663296);
        bf16*  vT   = (bf16*)(p + 125829120);

        // fused fp32 -> bf16 of all inputs (one launch)
        cvt5<<<24576, 256, 0, stream>>>(x, Wq, Wk, Wv, Wo, xb, Wqkv, Wob);

        // fused QKV projection: [2048 x 6144], 256x192 tiles, 8-phase pipeline
        gemm8<256, 192, 2, 4, 1, bf16><<<dim3(32, 8), 512, 0, stream>>>(
            xb, Wqkv, bq, bk, bv, qkv, QSTR, 4096);

        // LN + RoPE in place (q pre-scaled by QSCL)
        ln_rope<<<dim3((S_LEN * (NH + NKV)) / 4), 256, 0, stream>>>(qkv, qg, qbt, kg, kbt);

        // v -> vT
        transpose_v<<<dim3(16, 32), 256, 0, stream>>>(qkv, vT);

        // fused-split attention: bf16 output direct, no partials/merge
        attn4<<<dim3(32, 8), 512, 0, stream>>>(qkv, vT, abuf);

        // output projection: 256x128 tiles, 8-phase pipeline
        gemm8<256, 128, 4, 2, 0, float><<<dim3(32, 8), 512, 0, stream>>>(
            abuf, Wob, bo, bo, bo, out, 4096, 4096);
    } else {
        char* ws = (char*)d_ws;
        bf16* qbuf = (bf16*)(ws);
        bf16* kbuf = (bf16*)(ws + (16u << 20));
        bf16* vbuf = (bf16*)(ws + (20u << 20));
        bf16* abuf = (bf16*)(ws + (24u << 20));
        gemm_bt<float, bf16><<<dim3(32, 16), 256, 0, stream>>>(x, Wq, bq, qbuf, 4096, 4096);
        gemm_bt<float, bf16><<<dim3(8, 16), 256, 0, stream>>>(x, Wk, bk, kbuf, 1024, 4096);
        gemm_bt<float, bf16><<<dim3(8, 16), 256, 0, stream>>>(x, Wv, bv, vbuf, 1024, 4096);
        ln_rope_f<<<dim3((S_LEN * (NH + NKV)) / 4), 256, 0, stream>>>(qbuf, kbuf, qg, qbt, kg, kbt);
        attn_old<<<dim3(32, 32), 256, 0, stream>>>(qbuf, kbuf, vbuf, abuf);
        gemm_bt<bf16, float><<<dim3(32, 16), 256, 0, stream>>>(abuf, Wo, bo, out, 4096, 4096);
    }
}